// Round 1
// baseline (259.912 us; speedup 1.0000x reference)
//
#include <hip/hip_runtime.h>
#include <hip/hip_bf16.h>
#include <stdint.h>

// Problem constants
#define NB 4
#define NT 2048
#define NC 1024
#define NH 16
#define NHD 64
#define NM (NB*NT)   // 8192 rows

typedef __attribute__((ext_vector_type(8))) __bf16 bf16x8;
typedef __attribute__((ext_vector_type(4))) float floatx4;
typedef __attribute__((ext_vector_type(8))) unsigned short ushortx8;

#define AS1(p) ((const __attribute__((address_space(1))) void*)(p))
#define AS3(p) ((__attribute__((address_space(3))) void*)(p))

__device__ __forceinline__ unsigned short f2bf(float f) {
    union { float f; unsigned int u; } v; v.f = f;
    unsigned int u = v.u;
    return (unsigned short)((u + 0x7FFFu + ((u >> 16) & 1u)) >> 16);
}
// pack two fp32 -> (bf16(hi)<<16)|bf16(lo), RTZ, single v_perm_b32
__device__ __forceinline__ unsigned int pk2(float lo, float hi) {
    union { float f; unsigned int u; } a, b; a.f = hi; b.f = lo;
    return __builtin_amdgcn_perm(a.u, b.u, 0x07060302u);
}

// ===== fragment-tiled layout (for all GEMM operands) =====
// matrix (rows x 1024 cols) stored as 16x32 tiles of 512 shorts:
//   tile (R=row/16, C=col/32) at offset (R*32 + C)*512
//   element (r=row&15, c=col&31) at ((c>>3)*16 + r)*8 + (c&7)

// ---------------- cast fp32 -> bf16, fragment-tiled (1 tile per wave) -------
__global__ void cast_x_tiled(const float* __restrict__ in,
                             unsigned short* __restrict__ out, int ntiles) {
    const int wid  = (blockIdx.x * blockDim.x + threadIdx.x) >> 6;
    const int lane = threadIdx.x & 63;
    if (wid >= ntiles) return;
    const int R = wid >> 5, C = wid & 31;
    const float* src = in + ((size_t)(R*16 + (lane >> 2)))*1024 + C*32 + (lane & 3)*8;
    const floatx4 v0 = *(const floatx4*)src;
    const floatx4 v1 = *(const floatx4*)(src + 4);
    ushortx8 o;
    o[0] = f2bf(v0[0]); o[1] = f2bf(v0[1]); o[2] = f2bf(v0[2]); o[3] = f2bf(v0[3]);
    o[4] = f2bf(v1[0]); o[5] = f2bf(v1[1]); o[6] = f2bf(v1[2]); o[7] = f2bf(v1[3]);
    *(ushortx8*)&out[(size_t)wid*512 + (((lane & 3)*16 + (lane >> 2)))*8] = o;
}

__global__ void cast4_tiled(const float* __restrict__ w0, const float* __restrict__ w1,
                            const float* __restrict__ w2, const float* __restrict__ w3,
                            unsigned short* __restrict__ o0, unsigned short* __restrict__ o1,
                            unsigned short* __restrict__ o2, unsigned short* __restrict__ o3,
                            int ntiles) {
    const int wid  = (blockIdx.x * blockDim.x + threadIdx.x) >> 6;
    const int lane = threadIdx.x & 63;
    if (wid >= ntiles) return;
    const float* in; unsigned short* out;
    switch (blockIdx.y) {
        case 0: in = w0; out = o0; break;
        case 1: in = w1; out = o1; break;
        case 2: in = w2; out = o2; break;
        default: in = w3; out = o3; break;
    }
    const int R = wid >> 5, C = wid & 31;
    const float* src = in + ((size_t)(R*16 + (lane >> 2)))*1024 + C*32 + (lane & 3)*8;
    const floatx4 v0 = *(const floatx4*)src;
    const floatx4 v1 = *(const floatx4*)(src + 4);
    ushortx8 o;
    o[0] = f2bf(v0[0]); o[1] = f2bf(v0[1]); o[2] = f2bf(v0[2]); o[3] = f2bf(v0[3]);
    o[4] = f2bf(v1[0]); o[5] = f2bf(v1[1]); o[6] = f2bf(v1[2]); o[7] = f2bf(v1[3]);
    *(ushortx8*)&out[(size_t)wid*512 + (((lane & 3)*16 + (lane >> 2)))*8] = o;
}

// ---------------- GEMM core (used by gemm_out): Out = (A @ W^T + bias) ------
#define TM 128
#define TN 128
#define BK 32

__device__ __forceinline__ void gemm_core(
    const unsigned short* __restrict__ A,
    const unsigned short* __restrict__ W,
    const float* __restrict__ bias,
    void* __restrict__ Out,
    unsigned short* As, unsigned short* Bs,
    int m_base, int n_base, int N_out, int K, int mode, float oscale)
{
    const int tid  = threadIdx.x;
    const int lane = tid & 63;
    const int wv   = tid >> 6;
    const int quad = lane >> 4;
    const int l16  = lane & 15;
    const int wm = (wv >> 1) * 64;
    const int wn = (wv & 1) * 64;

    floatx4 acc[4][4];
    #pragma unroll
    for (int i = 0; i < 4; ++i)
        #pragma unroll
        for (int j = 0; j < 4; ++j)
            acc[i][j] = (floatx4){0.f, 0.f, 0.f, 0.f};

    const int kTiles = K / BK;
    const int kct = K >> 5;

    const unsigned short* At = A + ((size_t)((m_base >> 4) + wv*2) * kct) * 512 + (size_t)lane*8;
    const unsigned short* Wt = W + ((size_t)((n_base >> 4) + wv*2) * kct) * 512 + (size_t)lane*8;
    const size_t rstride = (size_t)kct * 512;

    for (int kt = 0; kt < kTiles; ++kt) {
        __syncthreads();
        #pragma unroll
        for (int i = 0; i < 2; ++i) {
            __builtin_amdgcn_global_load_lds(
                AS1(At + (size_t)kt*512 + i*rstride),
                AS3(&As[(wv*2 + i)*512]), 16, 0, 0);
            __builtin_amdgcn_global_load_lds(
                AS1(Wt + (size_t)kt*512 + i*rstride),
                AS3(&Bs[(wv*2 + i)*512]), 16, 0, 0);
        }
        __syncthreads();

        bf16x8 af[4], bfr[4];
        #pragma unroll
        for (int mi = 0; mi < 4; ++mi)
            af[mi] = *(const bf16x8*)&As[((wv >> 1)*4 + mi)*512 + lane*8];
        #pragma unroll
        for (int ni = 0; ni < 4; ++ni)
            bfr[ni] = *(const bf16x8*)&Bs[((wv & 1)*4 + ni)*512 + lane*8];

        #pragma unroll
        for (int mi = 0; mi < 4; ++mi)
            #pragma unroll
            for (int ni = 0; ni < 4; ++ni)
                acc[mi][ni] = __builtin_amdgcn_mfma_f32_16x16x32_bf16(
                    af[mi], bfr[ni], acc[mi][ni], 0, 0, 0);
    }

    // epilogue: C/D layout col = lane&15, row = quad*4 + reg
    #pragma unroll
    for (int mi = 0; mi < 4; ++mi) {
        #pragma unroll
        for (int ni = 0; ni < 4; ++ni) {
            const int col = n_base + wn + ni*16 + l16;
            const float bv = bias[col & 1023];
            #pragma unroll
            for (int r = 0; r < 4; ++r) {
                const int row = m_base + wm + mi*16 + quad*4 + r;
                const float v = (acc[mi][ni][r] + bv) * oscale;
                if (mode == 0) {
                    ((float*)Out)[(size_t)row * N_out + col] = v;
                } else if (mode == 1) {
                    const int bb = row >> 11, t = row & (NT - 1);
                    const int h  = (col >> 6) & (NH - 1), d = col & 63;
                    const int bh = bb * NH + h;
                    const size_t idx =
                        ((size_t)((bh*128 + (t >> 4))*2 + (d >> 5)))*512
                        + (size_t)((((d >> 3) & 3)*16 + (t & 15))*8 + (d & 7));
                    ((unsigned short*)Out)[idx] = f2bf(v);
                } else {
                    const int bb = row >> 11, t = row & (NT - 1);
                    const int h  = (col >> 6) & (NH - 1), hd = col & 63;
                    const int bh = bb * NH + h;
                    const int tk = t & 31;
                    const int qv = (tk >> 2) & 3;
                    const int jv = (tk & 3) + ((tk >> 4) << 2);
                    const size_t idx =
                        ((size_t)((bh*64 + (t >> 5))*4 + (hd >> 4)))*512
                        + (size_t)((qv*16 + (hd & 15))*8 + jv);
                    ((unsigned short*)Out)[idx] = f2bf(v);
                }
            }
        }
    }
}

#define QSCALE (0.03125f * 1.44269504088896340736f)   // (1/sqrt(C)) * log2(e)

// ---------------- fused QKV GEMM, 256x256 8-phase counted-vmcnt pipeline ----
// BM=BN=256, BK=64, 512 threads = 8 waves (2M x 4N), wave tile 128x64.
// LDS: 2 x (A 32KB + B 32KB) = 128KB, fragment tiles (1KB) linear ->
// conflict-free ds_read_b128 (T2 property by layout), global_load_lds direct.
// Per wave per K-tile: 8 staged tiles in fixed order (ks0: A,A,B,B; ks1:
// A,A,B,B) so vmcnt(4) at end of ph1/ph3 completes exactly the half-K-tile
// needed next while the 4 newest next-tile loads stay in flight (T4).
// grid (32, 12): blockIdx.y>>2 selects Q/K/V; &3 selects the 256-col slab.
__global__ __launch_bounds__(512, 2) void gemm_qkv8(
    const unsigned short* __restrict__ A,
    const unsigned short* __restrict__ Wq, const unsigned short* __restrict__ Wk,
    const unsigned short* __restrict__ Wv,
    const float* __restrict__ bq, const float* __restrict__ bk,
    const float* __restrict__ bv,
    unsigned short* __restrict__ Qo, unsigned short* __restrict__ Ko,
    unsigned short* __restrict__ Vo)
{
    __shared__ __align__(16) unsigned short As[2][16*2*512];   // 2 x 32KB
    __shared__ __align__(16) unsigned short Bs[2][16*2*512];   // 2 x 32KB

    const int tid  = threadIdx.x;
    const int lane = tid & 63;
    const int wave = tid >> 6;          // 0..7
    const int wm   = wave >> 2;         // 0..1  (M half)
    const int wn   = wave & 3;          // 0..3  (N quarter)
    const int quad = lane >> 4;
    const int l16  = lane & 15;

    const int wsel = blockIdx.y >> 2;
    const unsigned short* W; const float* bias; unsigned short* Out;
    int mode; float osc;
    if (wsel == 0)      { W = Wq; bias = bq; Out = Qo; mode = 1; osc = QSCALE; }
    else if (wsel == 1) { W = Wk; bias = bk; Out = Ko; mode = 1; osc = 1.0f; }
    else                { W = Wv; bias = bv; Out = Vo; mode = 2; osc = 1.0f; }

    const int Rb  = blockIdx.x * 16;          // A row-tile base (of 512)
    const int CTb = (blockIdx.y & 3) * 16;    // W row-tile base within weight

    const unsigned short* Ag = A + (size_t)lane * 8;
    const unsigned short* Wg = W + (size_t)lane * 8;

    const int jA  = wm*8 + wn*2;   // the 2 A row-tiles this wave stages
    const int ctB = wn*4 + wm*2;   // the 2 B col-tiles this wave stages

    floatx4 acc[8][4];
    #pragma unroll
    for (int i = 0; i < 8; ++i)
        #pragma unroll
        for (int j = 0; j < 4; ++j)
            acc[i][j] = (floatx4){0.f, 0.f, 0.f, 0.f};

#define SA(nbuf, j, C) __builtin_amdgcn_global_load_lds( \
        AS1(Ag + ((size_t)(Rb + (j))*32 + (size_t)(C))*512), \
        AS3(&As[nbuf][((j)*2 + ((C)&1))*512]), 16, 0, 0)
#define SB(nbuf, ct, C) __builtin_amdgcn_global_load_lds( \
        AS1(Wg + ((size_t)(CTb + (ct))*32 + (size_t)(C))*512), \
        AS3(&Bs[nbuf][((ct)*2 + ((C)&1))*512]), 16, 0, 0)

    // prologue: stage tile 0 (per-wave order L0..L7 = ks0 A,A,B,B; ks1 A,A,B,B)
    SA(0, jA, 0); SA(0, jA+1, 0); SB(0, ctB, 0); SB(0, ctB+1, 0);
    SA(0, jA, 1); SA(0, jA+1, 1); SB(0, ctB, 1); SB(0, ctB+1, 1);
    asm volatile("s_waitcnt vmcnt(4)" ::: "memory");   // L0..L3 (ks0) landed
    __builtin_amdgcn_s_barrier();

    #pragma unroll 1
    for (int kt = 0; kt < 16; ++kt) {
        const int cur = kt & 1, nbf = cur ^ 1;
        const int C0 = 2*(kt+1), C1 = 2*(kt+1) + 1;   // stage targets (tile kt+1)
        const bool nl = (kt < 15);
        bf16x8 a[4], b[4];

        // ---- phase 0: ks0, A rows 0-3 + all B(ks0); stage next A(ks0) ----
        #pragma unroll
        for (int i = 0; i < 4; ++i)
            a[i] = *(const bf16x8*)&As[cur][((wm*8 + i)*2 + 0)*512 + lane*8];
        #pragma unroll
        for (int i = 0; i < 4; ++i)
            b[i] = *(const bf16x8*)&Bs[cur][((wn*4 + i)*2 + 0)*512 + lane*8];
        if (nl) { SA(nbf, jA, C0); SA(nbf, jA+1, C0); }
        __builtin_amdgcn_s_barrier();
        __builtin_amdgcn_s_setprio(1);
        #pragma unroll
        for (int i = 0; i < 4; ++i)
            #pragma unroll
            for (int j = 0; j < 4; ++j)
                acc[i][j] = __builtin_amdgcn_mfma_f32_16x16x32_bf16(
                    a[i], b[j], acc[i][j], 0, 0, 0);
        __builtin_amdgcn_s_setprio(0);
        __builtin_amdgcn_s_barrier();

        // ---- phase 1: ks0, A rows 4-7; stage next B(ks0) ----
        #pragma unroll
        for (int i = 0; i < 4; ++i)
            a[i] = *(const bf16x8*)&As[cur][((wm*8 + 4 + i)*2 + 0)*512 + lane*8];
        if (nl) { SB(nbf, ctB, C0); SB(nbf, ctB+1, C0); }
        __builtin_amdgcn_s_barrier();
        __builtin_amdgcn_s_setprio(1);
        #pragma unroll
        for (int i = 0; i < 4; ++i)
            #pragma unroll
            for (int j = 0; j < 4; ++j)
                acc[4+i][j] = __builtin_amdgcn_mfma_f32_16x16x32_bf16(
                    a[i], b[j], acc[4+i][j], 0, 0, 0);
        __builtin_amdgcn_s_setprio(0);
        // complete this tile's ks1 loads (oldest 4); next-tile ks0 stays in flight
        if (nl) asm volatile("s_waitcnt vmcnt(4)" ::: "memory");
        else    asm volatile("s_waitcnt vmcnt(0)" ::: "memory");
        __builtin_amdgcn_s_barrier();

        // ---- phase 2: ks1, A rows 0-3 + all B(ks1); stage next A(ks1) ----
        #pragma unroll
        for (int i = 0; i < 4; ++i)
            a[i] = *(const bf16x8*)&As[cur][((wm*8 + i)*2 + 1)*512 + lane*8];
        #pragma unroll
        for (int i = 0; i < 4; ++i)
            b[i] = *(const bf16x8*)&Bs[cur][((wn*4 + i)*2 + 1)*512 + lane*8];
        if (nl) { SA(nbf, jA, C1); SA(nbf, jA+1, C1); }
        __builtin_amdgcn_s_barrier();
        __builtin_amdgcn_s_setprio(1);
        #pragma unroll
        for (int i = 0; i < 4; ++i)
            #pragma unroll
            for (int j = 0; j < 4; ++j)
                acc[i][j] = __builtin_amdgcn_mfma_f32_16x16x32_bf16(
                    a[i], b[j], acc[i][j], 0, 0, 0);
        __builtin_amdgcn_s_setprio(0);
        __builtin_amdgcn_s_barrier();

        // ---- phase 3: ks1, A rows 4-7; stage next B(ks1) ----
        #pragma unroll
        for (int i = 0; i < 4; ++i)
            a[i] = *(const bf16x8*)&As[cur][((wm*8 + 4 + i)*2 + 1)*512 + lane*8];
        if (nl) { SB(nbf, ctB, C1); SB(nbf, ctB+1, C1); }
        __builtin_amdgcn_s_barrier();
        __builtin_amdgcn_s_setprio(1);
        #pragma unroll
        for (int i = 0; i < 4; ++i)
            #pragma unroll
            for (int j = 0; j < 4; ++j)
                acc[4+i][j] = __builtin_amdgcn_mfma_f32_16x16x32_bf16(
                    a[i], b[j], acc[4+i][j], 0, 0, 0);
        __builtin_amdgcn_s_setprio(0);
        if (nl) {
            // next tile's ks0 (L0..L3) landed; its ks1 (L4..L7) stays in flight
            asm volatile("s_waitcnt vmcnt(4)" ::: "memory");
            __builtin_amdgcn_s_barrier();
        }
    }
#undef SA
#undef SB

    // epilogue: C/D layout col = lane&15, row = quad*4 + reg
    #pragma unroll
    for (int rf = 0; rf < 8; ++rf) {
        #pragma unroll
        for (int cf = 0; cf < 4; ++cf) {
            const int col = CTb*16 + wn*64 + cf*16 + l16;   // 0..1023 in weight
            const float bvv = bias[col];
            #pragma unroll
            for (int r = 0; r < 4; ++r) {
                const int row = Rb*16 + wm*128 + rf*16 + quad*4 + r;
                const float v = (acc[rf][cf][r] + bvv) * osc;
                if (mode == 1) {
                    const int bb = row >> 11, t = row & (NT - 1);
                    const int h  = (col >> 6) & (NH - 1), d = col & 63;
                    const int bh = bb * NH + h;
                    const size_t idx =
                        ((size_t)((bh*128 + (t >> 4))*2 + (d >> 5)))*512
                        + (size_t)((((d >> 3) & 3)*16 + (t & 15))*8 + (d & 7));
                    Out[idx] = f2bf(v);
                } else {
                    const int bb = row >> 11, t = row & (NT - 1);
                    const int h  = (col >> 6) & (NH - 1), hd = col & 63;
                    const int bh = bb * NH + h;
                    const int tk = t & 31;
                    const int qv = (tk >> 2) & 3;
                    const int jv = (tk & 3) + ((tk >> 4) << 2);
                    const size_t idx =
                        ((size_t)((bh*64 + (t >> 5))*4 + (hd >> 4)))*512
                        + (size_t)((qv*16 + (hd & 15))*8 + jv);
                    Out[idx] = f2bf(v);
                }
            }
        }
    }
}

__global__ __launch_bounds__(256) void gemm_out(
    const unsigned short* __restrict__ A,
    const unsigned short* __restrict__ W,
    const float* __restrict__ bias,
    float* __restrict__ Out)
{
    __shared__ __align__(16) unsigned short As[TM*BK];
    __shared__ __align__(16) unsigned short Bs[TN*BK];
    gemm_core(A, W, bias, Out, As, Bs, blockIdx.x * TM, blockIdx.y * TN,
              NC, NC, 0, 1.0f);
}

// ---------------- flash attention (causal), transposed-P scheme -------------
__device__ __forceinline__ void attn_q32(
    const unsigned short* __restrict__ Qf,
    const unsigned short* __restrict__ Kf,
    const unsigned short* __restrict__ Vf,
    unsigned short* __restrict__ Y,      // fragment-tiled (B*T x 1024)
    int bh, int st, int lane)
{
    const int quad = lane >> 4, l16 = lane & 15;
    const int q0 = st * 32;
    const int b = bh >> 4, h = bh & (NH - 1);

    const size_t qbase = ((size_t)(bh*128 + st*2))*1024 + (size_t)lane*8;
    const bf16x8 qa0 = *(const bf16x8*)&Qf[qbase];
    const bf16x8 qa1 = *(const bf16x8*)&Qf[qbase + 512];
    const bf16x8 qb0 = *(const bf16x8*)&Qf[qbase + 1024];
    const bf16x8 qb1 = *(const bf16x8*)&Qf[qbase + 1536];

    const unsigned short* kp = Kf + (size_t)bh*131072 + (size_t)lane*8;
    const unsigned short* vp = Vf + (size_t)bh*131072 + (size_t)lane*8;

    floatx4 oa[4], ob[4];
    #pragma unroll
    for (int nt = 0; nt < 4; ++nt) {
        oa[nt] = (floatx4){0.f,0.f,0.f,0.f};
        ob[nt] = (floatx4){0.f,0.f,0.f,0.f};
    }
    float la = 0.f, lb = 0.f;

    const int Ffull = q0 >> 6;
    const int ntile = Ffull + 1;          // full tiles + one diagonal tile

    for (int f = 0; f < ntile; ++f) {
        const int j0 = f * 64;
        const bool diag = (f == Ffull);
        bf16x8 kf[4][2], vf[4][2];
        {
            const unsigned short* kt = kp + (size_t)(j0 >> 4) * 1024;
            #pragma unroll
            for (int ct = 0; ct < 4; ++ct) {
                kf[ct][0] = *(const bf16x8*)&kt[ct*1024];
                kf[ct][1] = *(const bf16x8*)&kt[ct*1024 + 512];
            }
            const unsigned short* vt = vp + (size_t)(j0 >> 5) * 2048;
            #pragma unroll
            for (int nt = 0; nt < 4; ++nt) {
                vf[nt][0] = *(const bf16x8*)&vt[nt*512];
                vf[nt][1] = *(const bf16x8*)&vt[2048 + nt*512];
            }
        }
        #pragma unroll
        for (int sub = 0; sub < 2; ++sub) {
            const bf16x8 qx0 = sub ? qb0 : qa0;
            const bf16x8 qx1 = sub ? qb1 : qa1;
            floatx4* ox = sub ? ob : oa;

            floatx4 s[4];
            #pragma unroll
            for (int ct = 0; ct < 4; ++ct) {
                s[ct] = (floatx4){0.f,0.f,0.f,0.f};
                s[ct] = __builtin_amdgcn_mfma_f32_16x16x32_bf16(kf[ct][0], qx0, s[ct], 0,0,0);
                s[ct] = __builtin_amdgcn_mfma_f32_16x16x32_bf16(kf[ct][1], qx1, s[ct], 0,0,0);
            }
            float p[4][4];
            float lsum = 0.f;
            if (!diag) {
                #pragma unroll
                for (int ct = 0; ct < 4; ++ct)
                    #pragma unroll
                    for (int r = 0; r < 4; ++r) {
                        p[ct][r] = __builtin_amdgcn_exp2f(s[ct][r]);
                        lsum += p[ct][r];
                    }
            } else {
                const int row = q0 + sub*16 + l16;
                #pragma unroll
                for (int ct = 0; ct < 4; ++ct)
                    #pragma unroll
                    for (int r = 0; r < 4; ++r) {
                        const int key = j0 + ct*16 + quad*4 + r;
                        p[ct][r] = (key <= row) ? __builtin_amdgcn_exp2f(s[ct][r]) : 0.f;
                        lsum += p[ct][r];
                    }
            }
            if (sub) lb += lsum; else la += lsum;

            union { bf16x8 v; unsigned int u[4]; } pf0, pf1;
            pf0.u[0] = pk2(p[0][0], p[0][1]); pf0.u[1] = pk2(p[0][2], p[0][3]);
            pf0.u[2] = pk2(p[1][0], p[1][1]); pf0.u[3] = pk2(p[1][2], p[1][3]);
            pf1.u[0] = pk2(p[2][0], p[2][1]); pf1.u[1] = pk2(p[2][2], p[2][3]);
            pf1.u[2] = pk2(p[3][0], p[3][1]); pf1.u[3] = pk2(p[3][2], p[3][3]);

            #pragma unroll
            for (int nt = 0; nt < 4; ++nt) {
                ox[nt] = __builtin_amdgcn_mfma_f32_16x16x32_bf16(vf[nt][0], pf0.v, ox[nt], 0,0,0);
                ox[nt] = __builtin_amdgcn_mfma_f32_16x16x32_bf16(vf[nt][1], pf1.v, ox[nt], 0,0,0);
            }
        }
    }

    // row-sum: reduce across quads only (lanes with same l16)
    la += __shfl_xor(la, 16); la += __shfl_xor(la, 32);
    lb += __shfl_xor(lb, 16); lb += __shfl_xor(lb, 32);
    const float ia = 1.0f / la, ib = 1.0f / lb;

    const size_t Rbase = (size_t)((b*NT + q0) >> 4);
    const int cg = (quad >> 1), co = (quad & 1)*4;
    #pragma unroll
    for (int nt = 0; nt < 4; ++nt) {
        const size_t base = ((Rbase*32 + h*2 + (nt >> 1))*512)
                          + (size_t)((((nt & 1)*2 + cg)*16 + l16)*8 + co);
        ushort4 wa, wb;
        wa.x = f2bf(oa[nt][0]*ia); wa.y = f2bf(oa[nt][1]*ia);
        wa.z = f2bf(oa[nt][2]*ia); wa.w = f2bf(oa[nt][3]*ia);
        wb.x = f2bf(ob[nt][0]*ib); wb.y = f2bf(ob[nt][1]*ib);
        wb.z = f2bf(ob[nt][2]*ib); wb.w = f2bf(ob[nt][3]*ib);
        *(ushort4*)&Y[base]         = wa;
        *(ushort4*)&Y[base + 16384] = wb;   // +1 row-tile (32*512)
    }
}

__global__ __launch_bounds__(256) void flash_attn(
    const unsigned short* __restrict__ Qf,
    const unsigned short* __restrict__ Kf,
    const unsigned short* __restrict__ Vf,
    unsigned short* __restrict__ Y)
{
    const int tid  = threadIdx.x;
    const int wave = tid >> 6;
    const int lane = tid & 63;
    const int bh = blockIdx.y;
    const int w = blockIdx.x * 4 + wave;   // 0..31
    attn_q32(Qf, Kf, Vf, Y, bh, w, lane);
    attn_q32(Qf, Kf, Vf, Y, bh, 63 - w, lane);
}

// ---------------- launch ----------------
extern "C" void kernel_launch(void* const* d_in, const int* in_sizes, int n_in,
                              void* d_out, int out_size, void* d_ws, size_t ws_size,
                              hipStream_t stream) {
    const float* x  = (const float*)d_in[0];
    const float* Wq = (const float*)d_in[1];
    const float* bq = (const float*)d_in[2];
    const float* Wk = (const float*)d_in[3];
    const float* bk = (const float*)d_in[4];
    const float* Wv = (const float*)d_in[5];
    const float* bv = (const float*)d_in[6];
    const float* Wo = (const float*)d_in[7];
    const float* bo = (const float*)d_in[8];

    char* ws = (char*)d_ws;
    size_t off = 0;
    auto alloc = [&](size_t bytes) -> void* {
        void* p = ws + off;
        off += (bytes + 255) & ~(size_t)255;
        return p;
    };
    unsigned short* xb  = (unsigned short*)alloc((size_t)NM * NC * 2);
    unsigned short* Wqb = (unsigned short*)alloc((size_t)NC * NC * 2);
    unsigned short* Wkb = (unsigned short*)alloc((size_t)NC * NC * 2);
    unsigned short* Wvb = (unsigned short*)alloc((size_t)NC * NC * 2);
    unsigned short* Wob = (unsigned short*)alloc((size_t)NC * NC * 2);
    unsigned short* Qb  = (unsigned short*)alloc((size_t)NM * NC * 2);
    unsigned short* Kb  = (unsigned short*)alloc((size_t)NM * NC * 2);
    unsigned short* Vtb = (unsigned short*)alloc((size_t)NM * NC * 2);
    unsigned short* Yb  = (unsigned short*)alloc((size_t)NM * NC * 2);

    const int ntx = NM * NC / 512;   // 16384 tiles
    const int ntw = NC * NC / 512;   // 2048 tiles per weight
    cast_x_tiled<<<(ntx*64 + 255)/256, 256, 0, stream>>>(x, xb, ntx);
    cast4_tiled<<<dim3((ntw*64 + 255)/256, 4), 256, 0, stream>>>(
        Wq, Wk, Wv, Wo, Wqb, Wkb, Wvb, Wob, ntw);

    gemm_qkv8<<<dim3(NM / 256, 12), 512, 0, stream>>>(
        xb, Wqb, Wkb, Wvb, bq, bk, bv, Qb, Kb, Vtb);

    flash_attn<<<dim3(8, NB*NH), 256, 0, stream>>>(Qb, Kb, Vtb, Yb);

    gemm_out<<<dim3(NM / TM, NC / TN), 256, 0, stream>>>(Yb, Wob, bo, (float*)d_out);
}

// Round 2
// 241.770 us; speedup vs baseline: 1.0750x; 1.0750x over previous
//
#include <hip/hip_runtime.h>
#include <hip/hip_bf16.h>
#include <stdint.h>

// Problem constants
#define NB 4
#define NT 2048
#define NC 1024
#define NH 16
#define NHD 64
#define NM (NB*NT)   // 8192 rows

typedef __attribute__((ext_vector_type(8))) __bf16 bf16x8;
typedef __attribute__((ext_vector_type(4))) float floatx4;
typedef __attribute__((ext_vector_type(8))) unsigned short ushortx8;

#define AS1(p) ((const __attribute__((address_space(1))) void*)(p))
#define AS3(p) ((__attribute__((address_space(3))) void*)(p))

__device__ __forceinline__ unsigned short f2bf(float f) {
    union { float f; unsigned int u; } v; v.f = f;
    unsigned int u = v.u;
    return (unsigned short)((u + 0x7FFFu + ((u >> 16) & 1u)) >> 16);
}
// pack two fp32 -> (bf16(hi)<<16)|bf16(lo), RTZ, single v_perm_b32
__device__ __forceinline__ unsigned int pk2(float lo, float hi) {
    union { float f; unsigned int u; } a, b; a.f = hi; b.f = lo;
    return __builtin_amdgcn_perm(a.u, b.u, 0x07060302u);
}

// ===== fragment-tiled layout (for all GEMM operands) =====
// matrix (rows x 1024 cols) stored as 16x32 tiles of 512 shorts:
//   tile (R=row/16, C=col/32) at offset (R*32 + C)*512
//   element (r=row&15, c=col&31) at ((c>>3)*16 + r)*8 + (c&7)

// ---------------- cast fp32 -> bf16, fragment-tiled (1 tile per wave) -------
__global__ void cast_x_tiled(const float* __restrict__ in,
                             unsigned short* __restrict__ out, int ntiles) {
    const int wid  = (blockIdx.x * blockDim.x + threadIdx.x) >> 6;
    const int lane = threadIdx.x & 63;
    if (wid >= ntiles) return;
    const int R = wid >> 5, C = wid & 31;
    const float* src = in + ((size_t)(R*16 + (lane >> 2)))*1024 + C*32 + (lane & 3)*8;
    const floatx4 v0 = *(const floatx4*)src;
    const floatx4 v1 = *(const floatx4*)(src + 4);
    ushortx8 o;
    o[0] = f2bf(v0[0]); o[1] = f2bf(v0[1]); o[2] = f2bf(v0[2]); o[3] = f2bf(v0[3]);
    o[4] = f2bf(v1[0]); o[5] = f2bf(v1[1]); o[6] = f2bf(v1[2]); o[7] = f2bf(v1[3]);
    *(ushortx8*)&out[(size_t)wid*512 + (((lane & 3)*16 + (lane >> 2)))*8] = o;
}

__global__ void cast4_tiled(const float* __restrict__ w0, const float* __restrict__ w1,
                            const float* __restrict__ w2, const float* __restrict__ w3,
                            unsigned short* __restrict__ o0, unsigned short* __restrict__ o1,
                            unsigned short* __restrict__ o2, unsigned short* __restrict__ o3,
                            int ntiles) {
    const int wid  = (blockIdx.x * blockDim.x + threadIdx.x) >> 6;
    const int lane = threadIdx.x & 63;
    if (wid >= ntiles) return;
    const float* in; unsigned short* out;
    switch (blockIdx.y) {
        case 0: in = w0; out = o0; break;
        case 1: in = w1; out = o1; break;
        case 2: in = w2; out = o2; break;
        default: in = w3; out = o3; break;
    }
    const int R = wid >> 5, C = wid & 31;
    const float* src = in + ((size_t)(R*16 + (lane >> 2)))*1024 + C*32 + (lane & 3)*8;
    const floatx4 v0 = *(const floatx4*)src;
    const floatx4 v1 = *(const floatx4*)(src + 4);
    ushortx8 o;
    o[0] = f2bf(v0[0]); o[1] = f2bf(v0[1]); o[2] = f2bf(v0[2]); o[3] = f2bf(v0[3]);
    o[4] = f2bf(v1[0]); o[5] = f2bf(v1[1]); o[6] = f2bf(v1[2]); o[7] = f2bf(v1[3]);
    *(ushortx8*)&out[(size_t)wid*512 + (((lane & 3)*16 + (lane >> 2)))*8] = o;
}

// ---------------- GEMM core: Out = (A @ W^T + bias) * oscale ----------------
// A, W fragment-tiled, K=1024. BK=32, 16KB LDS, conflict-free (r8).
// mode 0: Out fp32 row-major MxN (final projection)
// mode 1: Out bf16 in MFMA A/B-fragment order for Q/K
// mode 2: Out bf16 V^T A-frag order, key-permuted for the P^T PV scheme
// NOTE (R1 post-mortem): the 256x256 8-phase/counted-vmcnt rewrite of this
// kernel REGRESSED 73.5 -> 102 us: LDS 128KB -> 1 block/CU killed the
// inter-block overlap (m114) that this 16KB/6-blocks-per-CU structure relies
// on, and 384 blocks @ 1/CU added a 2-round imbalance. Keep this structure.
#define TM 128
#define TN 128
#define BK 32

__device__ __forceinline__ void gemm_core(
    const unsigned short* __restrict__ A,
    const unsigned short* __restrict__ W,
    const float* __restrict__ bias,
    void* __restrict__ Out,
    unsigned short* As, unsigned short* Bs,
    int m_base, int n_base, int N_out, int K, int mode, float oscale)
{
    const int tid  = threadIdx.x;
    const int lane = tid & 63;
    const int wv   = tid >> 6;
    const int quad = lane >> 4;
    const int l16  = lane & 15;
    const int wm = (wv >> 1) * 64;
    const int wn = (wv & 1) * 64;

    floatx4 acc[4][4];
    #pragma unroll
    for (int i = 0; i < 4; ++i)
        #pragma unroll
        for (int j = 0; j < 4; ++j)
            acc[i][j] = (floatx4){0.f, 0.f, 0.f, 0.f};

    const int kTiles = K / BK;
    const int kct = K >> 5;

    const unsigned short* At = A + ((size_t)((m_base >> 4) + wv*2) * kct) * 512 + (size_t)lane*8;
    const unsigned short* Wt = W + ((size_t)((n_base >> 4) + wv*2) * kct) * 512 + (size_t)lane*8;
    const size_t rstride = (size_t)kct * 512;

    for (int kt = 0; kt < kTiles; ++kt) {
        __syncthreads();
        #pragma unroll
        for (int i = 0; i < 2; ++i) {
            __builtin_amdgcn_global_load_lds(
                AS1(At + (size_t)kt*512 + i*rstride),
                AS3(&As[(wv*2 + i)*512]), 16, 0, 0);
            __builtin_amdgcn_global_load_lds(
                AS1(Wt + (size_t)kt*512 + i*rstride),
                AS3(&Bs[(wv*2 + i)*512]), 16, 0, 0);
        }
        __syncthreads();

        bf16x8 af[4], bfr[4];
        #pragma unroll
        for (int mi = 0; mi < 4; ++mi)
            af[mi] = *(const bf16x8*)&As[((wv >> 1)*4 + mi)*512 + lane*8];
        #pragma unroll
        for (int ni = 0; ni < 4; ++ni)
            bfr[ni] = *(const bf16x8*)&Bs[((wv & 1)*4 + ni)*512 + lane*8];

        #pragma unroll
        for (int mi = 0; mi < 4; ++mi)
            #pragma unroll
            for (int ni = 0; ni < 4; ++ni)
                acc[mi][ni] = __builtin_amdgcn_mfma_f32_16x16x32_bf16(
                    af[mi], bfr[ni], acc[mi][ni], 0, 0, 0);
    }

    // epilogue: C/D layout col = lane&15, row = quad*4 + reg
    #pragma unroll
    for (int mi = 0; mi < 4; ++mi) {
        #pragma unroll
        for (int ni = 0; ni < 4; ++ni) {
            const int col = n_base + wn + ni*16 + l16;
            const float bv = bias[col & 1023];
            #pragma unroll
            for (int r = 0; r < 4; ++r) {
                const int row = m_base + wm + mi*16 + quad*4 + r;
                const float v = (acc[mi][ni][r] + bv) * oscale;
                if (mode == 0) {
                    ((float*)Out)[(size_t)row * N_out + col] = v;
                } else if (mode == 1) {
                    const int bb = row >> 11, t = row & (NT - 1);
                    const int h  = (col >> 6) & (NH - 1), d = col & 63;
                    const int bh = bb * NH + h;
                    const size_t idx =
                        ((size_t)((bh*128 + (t >> 4))*2 + (d >> 5)))*512
                        + (size_t)((((d >> 3) & 3)*16 + (t & 15))*8 + (d & 7));
                    ((unsigned short*)Out)[idx] = f2bf(v);
                } else {
                    const int bb = row >> 11, t = row & (NT - 1);
                    const int h  = (col >> 6) & (NH - 1), hd = col & 63;
                    const int bh = bb * NH + h;
                    const int tk = t & 31;
                    const int qv = (tk >> 2) & 3;
                    const int jv = (tk & 3) + ((tk >> 4) << 2);
                    const size_t idx =
                        ((size_t)((bh*64 + (t >> 5))*4 + (hd >> 4)))*512
                        + (size_t)((qv*16 + (hd & 15))*8 + jv);
                    ((unsigned short*)Out)[idx] = f2bf(v);
                }
            }
        }
    }
}

// Fused QKV: grid (64, 24); blockIdx.y: 0-7 Q, 8-15 K, 16-23 V
#define QSCALE (0.03125f * 1.44269504088896340736f)   // (1/sqrt(C)) * log2(e)

__global__ __launch_bounds__(256) void gemm_qkv(
    const unsigned short* __restrict__ A,
    const unsigned short* __restrict__ Wq, const unsigned short* __restrict__ Wk,
    const unsigned short* __restrict__ Wv,
    const float* __restrict__ bq, const float* __restrict__ bk,
    const float* __restrict__ bv,
    unsigned short* __restrict__ Qo, unsigned short* __restrict__ Ko,
    unsigned short* __restrict__ Vo)
{
    __shared__ __align__(16) unsigned short As[TM*BK];
    __shared__ __align__(16) unsigned short Bs[TN*BK];
    const int wi = blockIdx.y >> 3;
    const int n_base = (blockIdx.y & 7) * TN;
    const unsigned short* W; const float* bias; void* Out; int mode; float osc;
    if (wi == 0)      { W = Wq; bias = bq; Out = Qo; mode = 1; osc = QSCALE; }
    else if (wi == 1) { W = Wk; bias = bk; Out = Ko; mode = 1; osc = 1.0f; }
    else              { W = Wv; bias = bv; Out = Vo; mode = 2; osc = 1.0f; }
    gemm_core(A, W, bias, Out, As, Bs, blockIdx.x * TM, n_base, NC, NC, mode, osc);
}

__global__ __launch_bounds__(256) void gemm_out(
    const unsigned short* __restrict__ A,
    const unsigned short* __restrict__ W,
    const float* __restrict__ bias,
    float* __restrict__ Out)
{
    __shared__ __align__(16) unsigned short As[TM*BK];
    __shared__ __align__(16) unsigned short Bs[TN*BK];
    gemm_core(A, W, bias, Out, As, Bs, blockIdx.x * TM, blockIdx.y * TN,
              NC, NC, 0, 1.0f);
}

// ---------------- flash attention (causal), transposed-P scheme -------------
// S^T = mfma(A=K, B=Q) (identical fragment maps); C-layout of S^T: lane l16 =
// Q-row, quad*4+r = key. exp -> P^T; pack pairs (v_perm RTZ) directly into the
// B-operand of O^T = mfma(A=V^T(key-permuted), B=P^T). No LDS at all.
// T5: s_setprio(1) around the MFMA clusters (m191: +4-7% on independent-wave
// attention; NULL only on barrier-lockstep GEMMs).
__device__ __forceinline__ void attn_q32(
    const unsigned short* __restrict__ Qf,
    const unsigned short* __restrict__ Kf,
    const unsigned short* __restrict__ Vf,
    unsigned short* __restrict__ Y,      // fragment-tiled (B*T x 1024)
    int bh, int st, int lane)
{
    const int quad = lane >> 4, l16 = lane & 15;
    const int q0 = st * 32;
    const int b = bh >> 4, h = bh & (NH - 1);

    const size_t qbase = ((size_t)(bh*128 + st*2))*1024 + (size_t)lane*8;
    const bf16x8 qa0 = *(const bf16x8*)&Qf[qbase];
    const bf16x8 qa1 = *(const bf16x8*)&Qf[qbase + 512];
    const bf16x8 qb0 = *(const bf16x8*)&Qf[qbase + 1024];
    const bf16x8 qb1 = *(const bf16x8*)&Qf[qbase + 1536];

    const unsigned short* kp = Kf + (size_t)bh*131072 + (size_t)lane*8;
    const unsigned short* vp = Vf + (size_t)bh*131072 + (size_t)lane*8;

    floatx4 oa[4], ob[4];
    #pragma unroll
    for (int nt = 0; nt < 4; ++nt) {
        oa[nt] = (floatx4){0.f,0.f,0.f,0.f};
        ob[nt] = (floatx4){0.f,0.f,0.f,0.f};
    }
    float la = 0.f, lb = 0.f;

    const int Ffull = q0 >> 6;
    const int ntile = Ffull + 1;          // full tiles + one diagonal tile

    for (int f = 0; f < ntile; ++f) {
        const int j0 = f * 64;
        const bool diag = (f == Ffull);
        bf16x8 kf[4][2], vf[4][2];
        {
            const unsigned short* kt = kp + (size_t)(j0 >> 4) * 1024;
            #pragma unroll
            for (int ct = 0; ct < 4; ++ct) {
                kf[ct][0] = *(const bf16x8*)&kt[ct*1024];
                kf[ct][1] = *(const bf16x8*)&kt[ct*1024 + 512];
            }
            const unsigned short* vt = vp + (size_t)(j0 >> 5) * 2048;
            #pragma unroll
            for (int nt = 0; nt < 4; ++nt) {
                vf[nt][0] = *(const bf16x8*)&vt[nt*512];
                vf[nt][1] = *(const bf16x8*)&vt[2048 + nt*512];
            }
        }
        #pragma unroll
        for (int sub = 0; sub < 2; ++sub) {
            const bf16x8 qx0 = sub ? qb0 : qa0;
            const bf16x8 qx1 = sub ? qb1 : qa1;
            floatx4* ox = sub ? ob : oa;

            floatx4 s[4];
            __builtin_amdgcn_s_setprio(1);
            #pragma unroll
            for (int ct = 0; ct < 4; ++ct) {
                s[ct] = (floatx4){0.f,0.f,0.f,0.f};
                s[ct] = __builtin_amdgcn_mfma_f32_16x16x32_bf16(kf[ct][0], qx0, s[ct], 0,0,0);
                s[ct] = __builtin_amdgcn_mfma_f32_16x16x32_bf16(kf[ct][1], qx1, s[ct], 0,0,0);
            }
            __builtin_amdgcn_s_setprio(0);
            float p[4][4];
            float lsum = 0.f;
            if (!diag) {
                #pragma unroll
                for (int ct = 0; ct < 4; ++ct)
                    #pragma unroll
                    for (int r = 0; r < 4; ++r) {
                        p[ct][r] = __builtin_amdgcn_exp2f(s[ct][r]);
                        lsum += p[ct][r];
                    }
            } else {
                const int row = q0 + sub*16 + l16;
                #pragma unroll
                for (int ct = 0; ct < 4; ++ct)
                    #pragma unroll
                    for (int r = 0; r < 4; ++r) {
                        const int key = j0 + ct*16 + quad*4 + r;
                        p[ct][r] = (key <= row) ? __builtin_amdgcn_exp2f(s[ct][r]) : 0.f;
                        lsum += p[ct][r];
                    }
            }
            if (sub) lb += lsum; else la += lsum;

            union { bf16x8 v; unsigned int u[4]; } pf0, pf1;
            pf0.u[0] = pk2(p[0][0], p[0][1]); pf0.u[1] = pk2(p[0][2], p[0][3]);
            pf0.u[2] = pk2(p[1][0], p[1][1]); pf0.u[3] = pk2(p[1][2], p[1][3]);
            pf1.u[0] = pk2(p[2][0], p[2][1]); pf1.u[1] = pk2(p[2][2], p[2][3]);
            pf1.u[2] = pk2(p[3][0], p[3][1]); pf1.u[3] = pk2(p[3][2], p[3][3]);

            __builtin_amdgcn_s_setprio(1);
            #pragma unroll
            for (int nt = 0; nt < 4; ++nt) {
                ox[nt] = __builtin_amdgcn_mfma_f32_16x16x32_bf16(vf[nt][0], pf0.v, ox[nt], 0,0,0);
                ox[nt] = __builtin_amdgcn_mfma_f32_16x16x32_bf16(vf[nt][1], pf1.v, ox[nt], 0,0,0);
            }
            __builtin_amdgcn_s_setprio(0);
        }
    }

    // row-sum: reduce across quads only (lanes with same l16)
    la += __shfl_xor(la, 16); la += __shfl_xor(la, 32);
    lb += __shfl_xor(lb, 16); lb += __shfl_xor(lb, 32);
    const float ia = 1.0f / la, ib = 1.0f / lb;

    // O^T element: hd = nt*16 + quad*4 + r, row-in-subtile = l16.
    // Y fragment-tiled: 4 consecutive c per (nt,quad) -> one 8B store.
    const size_t Rbase = (size_t)((b*NT + q0) >> 4);
    const int cg = (quad >> 1), co = (quad & 1)*4;
    #pragma unroll
    for (int nt = 0; nt < 4; ++nt) {
        const size_t base = ((Rbase*32 + h*2 + (nt >> 1))*512)
                          + (size_t)((((nt & 1)*2 + cg)*16 + l16)*8 + co);
        ushort4 wa, wb;
        wa.x = f2bf(oa[nt][0]*ia); wa.y = f2bf(oa[nt][1]*ia);
        wa.z = f2bf(oa[nt][2]*ia); wa.w = f2bf(oa[nt][3]*ia);
        wb.x = f2bf(ob[nt][0]*ib); wb.y = f2bf(ob[nt][1]*ib);
        wb.z = f2bf(ob[nt][2]*ib); wb.w = f2bf(ob[nt][3]*ib);
        *(ushort4*)&Y[base]         = wa;
        *(ushort4*)&Y[base + 16384] = wb;   // +1 row-tile (32*512)
    }
}

// T1 XCD-grouping: 512 blocks, 1-D. Decode so all 8 blocks of one (b,h)
// share L % 8 (= XCD on the 8-XCD round-robin): bh depends only on L mod 64.
// bh = (L&7)*8 + ((L>>3)&7), x = L>>6  — bijective over 512.
// Each XCD then serves 8 heads' K/V (8 x 512KB = 4MB) from its own L2
// instead of every XCD re-fetching every head from L3.
__global__ __launch_bounds__(256) void flash_attn(
    const unsigned short* __restrict__ Qf,
    const unsigned short* __restrict__ Kf,
    const unsigned short* __restrict__ Vf,
    unsigned short* __restrict__ Y)
{
    const int tid  = threadIdx.x;
    const int wave = tid >> 6;
    const int lane = tid & 63;
    const int L  = blockIdx.x;
    const int bh = (L & 7) * 8 + ((L >> 3) & 7);
    const int x  = L >> 6;
    const int w  = x * 4 + wave;   // 0..31
    attn_q32(Qf, Kf, Vf, Y, bh, w, lane);
    attn_q32(Qf, Kf, Vf, Y, bh, 63 - w, lane);
}

// ---------------- launch ----------------
extern "C" void kernel_launch(void* const* d_in, const int* in_sizes, int n_in,
                              void* d_out, int out_size, void* d_ws, size_t ws_size,
                              hipStream_t stream) {
    const float* x  = (const float*)d_in[0];
    const float* Wq = (const float*)d_in[1];
    const float* bq = (const float*)d_in[2];
    const float* Wk = (const float*)d_in[3];
    const float* bk = (const float*)d_in[4];
    const float* Wv = (const float*)d_in[5];
    const float* bv = (const float*)d_in[6];
    const float* Wo = (const float*)d_in[7];
    const float* bo = (const float*)d_in[8];

    char* ws = (char*)d_ws;
    size_t off = 0;
    auto alloc = [&](size_t bytes) -> void* {
        void* p = ws + off;
        off += (bytes + 255) & ~(size_t)255;
        return p;
    };
    unsigned short* xb  = (unsigned short*)alloc((size_t)NM * NC * 2);
    unsigned short* Wqb = (unsigned short*)alloc((size_t)NC * NC * 2);
    unsigned short* Wkb = (unsigned short*)alloc((size_t)NC * NC * 2);
    unsigned short* Wvb = (unsigned short*)alloc((size_t)NC * NC * 2);
    unsigned short* Wob = (unsigned short*)alloc((size_t)NC * NC * 2);
    unsigned short* Qb  = (unsigned short*)alloc((size_t)NM * NC * 2);
    unsigned short* Kb  = (unsigned short*)alloc((size_t)NM * NC * 2);
    unsigned short* Vtb = (unsigned short*)alloc((size_t)NM * NC * 2);
    unsigned short* Yb  = (unsigned short*)alloc((size_t)NM * NC * 2);

    const int ntx = NM * NC / 512;   // 16384 tiles
    const int ntw = NC * NC / 512;   // 2048 tiles per weight
    cast_x_tiled<<<(ntx*64 + 255)/256, 256, 0, stream>>>(x, xb, ntx);
    cast4_tiled<<<dim3((ntw*64 + 255)/256, 4), 256, 0, stream>>>(
        Wq, Wk, Wv, Wo, Wqb, Wkb, Wvb, Wob, ntw);

    gemm_qkv<<<dim3(NM / TM, 24), 256, 0, stream>>>(
        xb, Wqb, Wkb, Wvb, bq, bk, bv, Qb, Kb, Vtb);

    flash_attn<<<dim3(512), 256, 0, stream>>>(Qb, Kb, Vtb, Yb);

    gemm_out<<<dim3(NM / TM, NC / TN), 256, 0, stream>>>(Yb, Wob, bo, (float*)d_out);
}

// Round 3
// 233.914 us; speedup vs baseline: 1.1111x; 1.0336x over previous
//
#include <hip/hip_runtime.h>
#include <hip/hip_bf16.h>
#include <stdint.h>

// Problem constants
#define NB 4
#define NT 2048
#define NC 1024
#define NH 16
#define NHD 64
#define NM (NB*NT)   // 8192 rows

typedef __attribute__((ext_vector_type(8))) __bf16 bf16x8;
typedef __attribute__((ext_vector_type(4))) float floatx4;
typedef __attribute__((ext_vector_type(8))) unsigned short ushortx8;

#define AS1(p) ((const __attribute__((address_space(1))) void*)(p))
#define AS3(p) ((__attribute__((address_space(3))) void*)(p))

__device__ __forceinline__ unsigned short f2bf(float f) {
    union { float f; unsigned int u; } v; v.f = f;
    unsigned int u = v.u;
    return (unsigned short)((u + 0x7FFFu + ((u >> 16) & 1u)) >> 16);
}
// pack two fp32 -> (bf16(hi)<<16)|bf16(lo), RTZ, single v_perm_b32
__device__ __forceinline__ unsigned int pk2(float lo, float hi) {
    union { float f; unsigned int u; } a, b; a.f = hi; b.f = lo;
    return __builtin_amdgcn_perm(a.u, b.u, 0x07060302u);
}

// ===== fragment-tiled layout (for all GEMM operands) =====
// matrix (rows x 1024 cols) stored as 16x32 tiles of 512 shorts:
//   tile (R=row/16, C=col/32) at offset (R*32 + C)*512
//   element (r=row&15, c=col&31) at ((c>>3)*16 + r)*8 + (c&7)

// ---------------- cast fp32 -> bf16, fragment-tiled (1 tile per wave) -------
__global__ void cast_x_tiled(const float* __restrict__ in,
                             unsigned short* __restrict__ out, int ntiles) {
    const int wid  = (blockIdx.x * blockDim.x + threadIdx.x) >> 6;
    const int lane = threadIdx.x & 63;
    if (wid >= ntiles) return;
    const int R = wid >> 5, C = wid & 31;
    const float* src = in + ((size_t)(R*16 + (lane >> 2)))*1024 + C*32 + (lane & 3)*8;
    const floatx4 v0 = *(const floatx4*)src;
    const floatx4 v1 = *(const floatx4*)(src + 4);
    ushortx8 o;
    o[0] = f2bf(v0[0]); o[1] = f2bf(v0[1]); o[2] = f2bf(v0[2]); o[3] = f2bf(v0[3]);
    o[4] = f2bf(v1[0]); o[5] = f2bf(v1[1]); o[6] = f2bf(v1[2]); o[7] = f2bf(v1[3]);
    *(ushortx8*)&out[(size_t)wid*512 + (((lane & 3)*16 + (lane >> 2)))*8] = o;
}

__global__ void cast4_tiled(const float* __restrict__ w0, const float* __restrict__ w1,
                            const float* __restrict__ w2, const float* __restrict__ w3,
                            unsigned short* __restrict__ o0, unsigned short* __restrict__ o1,
                            unsigned short* __restrict__ o2, unsigned short* __restrict__ o3,
                            int ntiles) {
    const int wid  = (blockIdx.x * blockDim.x + threadIdx.x) >> 6;
    const int lane = threadIdx.x & 63;
    if (wid >= ntiles) return;
    const float* in; unsigned short* out;
    switch (blockIdx.y) {
        case 0: in = w0; out = o0; break;
        case 1: in = w1; out = o1; break;
        case 2: in = w2; out = o2; break;
        default: in = w3; out = o3; break;
    }
    const int R = wid >> 5, C = wid & 31;
    const float* src = in + ((size_t)(R*16 + (lane >> 2)))*1024 + C*32 + (lane & 3)*8;
    const floatx4 v0 = *(const floatx4*)src;
    const floatx4 v1 = *(const floatx4*)(src + 4);
    ushortx8 o;
    o[0] = f2bf(v0[0]); o[1] = f2bf(v0[1]); o[2] = f2bf(v0[2]); o[3] = f2bf(v0[3]);
    o[4] = f2bf(v1[0]); o[5] = f2bf(v1[1]); o[6] = f2bf(v1[2]); o[7] = f2bf(v1[3]);
    *(ushortx8*)&out[(size_t)wid*512 + (((lane & 3)*16 + (lane >> 2)))*8] = o;
}

// ---------------- GEMM core: Out = (A @ W^T + bias) * oscale ----------------
// A, W fragment-tiled, K=1024. BK=32, 16KB LDS, conflict-free.
// MODE 0: Out fp32 row-major MxN (final projection)          [mfma(X, W)]
// MODE 1: Out bf16 Q/K fragment order. SWAPPED operands      [mfma(W, X)]
//         so the d-axis lands on the register quad -> ushort4 stores.
// MODE 2: Out bf16 V^T key-permuted A-frag order             [mfma(X, W)]
//         register axis r -> jv contiguous -> ushort4 stores.
// NOTE (R1 post-mortem): 256x256 8-phase/counted-vmcnt rewrite REGRESSED
// 73.5 -> 102 us (LDS 128KB -> 1 block/CU killed m114 inter-block overlap).
// Keep this 16KB / 6-blocks-per-CU structure.
#define TM 128
#define TN 128
#define BK 32

template<int MODE>
__device__ __forceinline__ void gemm_core(
    const unsigned short* __restrict__ A,
    const unsigned short* __restrict__ W,
    const float* __restrict__ bias,
    void* __restrict__ Out,
    unsigned short* As, unsigned short* Bs,
    int m_base, int n_base, float oscale)
{
    const int tid  = threadIdx.x;
    const int lane = tid & 63;
    const int wv   = tid >> 6;
    const int quad = lane >> 4;
    const int l16  = lane & 15;
    const int wm = (wv >> 1) * 64;
    const int wn = (wv & 1) * 64;

    floatx4 acc[4][4];
    #pragma unroll
    for (int i = 0; i < 4; ++i)
        #pragma unroll
        for (int j = 0; j < 4; ++j)
            acc[i][j] = (floatx4){0.f, 0.f, 0.f, 0.f};

    const int kTiles = NC / BK;
    const int kct = NC >> 5;

    const unsigned short* At = A + ((size_t)((m_base >> 4) + wv*2) * kct) * 512 + (size_t)lane*8;
    const unsigned short* Wt = W + ((size_t)((n_base >> 4) + wv*2) * kct) * 512 + (size_t)lane*8;
    const size_t rstride = (size_t)kct * 512;

    for (int kt = 0; kt < kTiles; ++kt) {
        __syncthreads();
        #pragma unroll
        for (int i = 0; i < 2; ++i) {
            __builtin_amdgcn_global_load_lds(
                AS1(At + (size_t)kt*512 + i*rstride),
                AS3(&As[(wv*2 + i)*512]), 16, 0, 0);
            __builtin_amdgcn_global_load_lds(
                AS1(Wt + (size_t)kt*512 + i*rstride),
                AS3(&Bs[(wv*2 + i)*512]), 16, 0, 0);
        }
        __syncthreads();

        bf16x8 af[4], bfr[4];
        #pragma unroll
        for (int mi = 0; mi < 4; ++mi)
            af[mi] = *(const bf16x8*)&As[((wv >> 1)*4 + mi)*512 + lane*8];
        #pragma unroll
        for (int ni = 0; ni < 4; ++ni)
            bfr[ni] = *(const bf16x8*)&Bs[((wv & 1)*4 + ni)*512 + lane*8];

        #pragma unroll
        for (int mi = 0; mi < 4; ++mi)
            #pragma unroll
            for (int ni = 0; ni < 4; ++ni) {
                if (MODE == 1)   // swapped: d on quad axis, t on l16
                    acc[mi][ni] = __builtin_amdgcn_mfma_f32_16x16x32_bf16(
                        bfr[ni], af[mi], acc[mi][ni], 0, 0, 0);
                else
                    acc[mi][ni] = __builtin_amdgcn_mfma_f32_16x16x32_bf16(
                        af[mi], bfr[ni], acc[mi][ni], 0, 0, 0);
            }
    }

    // epilogue
    #pragma unroll
    for (int mi = 0; mi < 4; ++mi) {
        #pragma unroll
        for (int ni = 0; ni < 4; ++ni) {
            if (MODE == 0) {
                // C/D: col = l16 (W-col), row = quad*4 + r (X-row)
                const int col = n_base + wn + ni*16 + l16;
                const float bv = bias[col & 1023];
                #pragma unroll
                for (int r = 0; r < 4; ++r) {
                    const int row = m_base + wm + mi*16 + quad*4 + r;
                    ((float*)Out)[(size_t)row * NC + col] =
                        (acc[mi][ni][r] + bv) * oscale;
                }
            } else if (MODE == 1) {
                // swapped: d = n_base+wn+ni*16+quad*4+r, t = m_base+wm+mi*16+l16
                const int d0 = n_base + wn + ni*16 + quad*4;
                const int t  = m_base + wm + mi*16 + l16;
                const float4 b4 = *(const float4*)&bias[d0];
                const int bb = t >> 11, tt = t & (NT - 1);
                const int h  = (d0 >> 6) & (NH - 1), dd0 = d0 & 63;
                const int bh = bb * NH + h;
                const size_t idx0 =
                    ((size_t)((bh*128 + (tt >> 4))*2 + (dd0 >> 5)))*512
                    + (size_t)((((dd0 >> 3) & 3)*16 + (tt & 15))*8 + (dd0 & 7));
                ushort4 st;
                st.x = f2bf((acc[mi][ni][0] + b4.x) * oscale);
                st.y = f2bf((acc[mi][ni][1] + b4.y) * oscale);
                st.z = f2bf((acc[mi][ni][2] + b4.z) * oscale);
                st.w = f2bf((acc[mi][ni][3] + b4.w) * oscale);
                *(ushort4*)&((unsigned short*)Out)[idx0] = st;
            } else {
                // unswapped: col const across r; r -> t -> jv contiguous
                const int col = n_base + wn + ni*16 + l16;
                const float bv = bias[col & 1023];
                const int row0 = m_base + wm + mi*16 + quad*4;
                const int bb = row0 >> 11, t0 = row0 & (NT - 1);
                const int h  = (col >> 6) & (NH - 1), hd = col & 63;
                const int bh = bb * NH + h;
                const int tk0 = t0 & 31;
                const int qv  = (tk0 >> 2) & 3;
                const int jv0 = (tk0 >> 4) << 2;      // tk0&3 == 0
                const size_t idx0 =
                    ((size_t)((bh*64 + (t0 >> 5))*4 + (hd >> 4)))*512
                    + (size_t)((qv*16 + (hd & 15))*8 + jv0);
                ushort4 st;
                st.x = f2bf((acc[mi][ni][0] + bv) * oscale);
                st.y = f2bf((acc[mi][ni][1] + bv) * oscale);
                st.z = f2bf((acc[mi][ni][2] + bv) * oscale);
                st.w = f2bf((acc[mi][ni][3] + bv) * oscale);
                *(ushort4*)&((unsigned short*)Out)[idx0] = st;
            }
        }
    }
}

// Fused QKV: grid (64, 24); blockIdx.y: 0-7 Q, 8-15 K, 16-23 V
#define QSCALE (0.03125f * 1.44269504088896340736f)   // (1/sqrt(C)) * log2(e)

__global__ __launch_bounds__(256) void gemm_qkv(
    const unsigned short* __restrict__ A,
    const unsigned short* __restrict__ Wq, const unsigned short* __restrict__ Wk,
    const unsigned short* __restrict__ Wv,
    const float* __restrict__ bq, const float* __restrict__ bk,
    const float* __restrict__ bv,
    unsigned short* __restrict__ Qo, unsigned short* __restrict__ Ko,
    unsigned short* __restrict__ Vo)
{
    __shared__ __align__(16) unsigned short As[TM*BK];
    __shared__ __align__(16) unsigned short Bs[TN*BK];
    const int wi = blockIdx.y >> 3;
    const int n_base = (blockIdx.y & 7) * TN;
    const int m_base = blockIdx.x * TM;
    if (wi == 0)
        gemm_core<1>(A, Wq, bq, Qo, As, Bs, m_base, n_base, QSCALE);
    else if (wi == 1)
        gemm_core<1>(A, Wk, bk, Ko, As, Bs, m_base, n_base, 1.0f);
    else
        gemm_core<2>(A, Wv, bv, Vo, As, Bs, m_base, n_base, 1.0f);
}

__global__ __launch_bounds__(256) void gemm_out(
    const unsigned short* __restrict__ A,
    const unsigned short* __restrict__ W,
    const float* __restrict__ bias,
    float* __restrict__ Out)
{
    __shared__ __align__(16) unsigned short As[TM*BK];
    __shared__ __align__(16) unsigned short Bs[TN*BK];
    gemm_core<0>(A, W, bias, Out, As, Bs, blockIdx.x * TM, blockIdx.y * TN, 1.0f);
}

// ---------------- flash attention (causal), transposed-P scheme -------------
// S^T = mfma(A=K, B=Q); C-layout of S^T: l16 = Q-row, quad*4+r = key.
// exp -> P^T; pack pairs (v_perm RTZ) into B-operand of O^T = mfma(V^T, P^T).
// No LDS. T5 setprio around MFMA clusters (m191).
// R3: strip-PAIR FUSION — each wave processes strips stA=w and stB=63-w in
// ONE f-loop sharing the K/V fragment loads (A's prefix is a subset of B's):
// 26% fewer K/V loads, 2x MFMA per loaded tile, same MFMA balance per wave.
__device__ __forceinline__ void attn_tile(
    const bf16x8 kf[4][2], const bf16x8 vf[4][2],
    const bf16x8 q[4], floatx4 o[2][4], float l[2],
    bool diag, int q0, int j0, int quad, int l16)
{
    #pragma unroll
    for (int sub = 0; sub < 2; ++sub) {
        const bf16x8 qx0 = q[sub*2];
        const bf16x8 qx1 = q[sub*2 + 1];

        floatx4 s[4];
        __builtin_amdgcn_s_setprio(1);
        #pragma unroll
        for (int ct = 0; ct < 4; ++ct) {
            s[ct] = (floatx4){0.f,0.f,0.f,0.f};
            s[ct] = __builtin_amdgcn_mfma_f32_16x16x32_bf16(kf[ct][0], qx0, s[ct], 0,0,0);
            s[ct] = __builtin_amdgcn_mfma_f32_16x16x32_bf16(kf[ct][1], qx1, s[ct], 0,0,0);
        }
        __builtin_amdgcn_s_setprio(0);

        float p[4][4];
        float lsum = 0.f;
        if (!diag) {
            #pragma unroll
            for (int ct = 0; ct < 4; ++ct)
                #pragma unroll
                for (int r = 0; r < 4; ++r) {
                    p[ct][r] = __builtin_amdgcn_exp2f(s[ct][r]);
                    lsum += p[ct][r];
                }
        } else {
            const int row = q0 + sub*16 + l16;
            #pragma unroll
            for (int ct = 0; ct < 4; ++ct)
                #pragma unroll
                for (int r = 0; r < 4; ++r) {
                    const int key = j0 + ct*16 + quad*4 + r;
                    p[ct][r] = (key <= row) ? __builtin_amdgcn_exp2f(s[ct][r]) : 0.f;
                    lsum += p[ct][r];
                }
        }
        l[sub] += lsum;

        union { bf16x8 v; unsigned int u[4]; } pf0, pf1;
        pf0.u[0] = pk2(p[0][0], p[0][1]); pf0.u[1] = pk2(p[0][2], p[0][3]);
        pf0.u[2] = pk2(p[1][0], p[1][1]); pf0.u[3] = pk2(p[1][2], p[1][3]);
        pf1.u[0] = pk2(p[2][0], p[2][1]); pf1.u[1] = pk2(p[2][2], p[2][3]);
        pf1.u[2] = pk2(p[3][0], p[3][1]); pf1.u[3] = pk2(p[3][2], p[3][3]);

        __builtin_amdgcn_s_setprio(1);
        #pragma unroll
        for (int nt = 0; nt < 4; ++nt) {
            o[sub][nt] = __builtin_amdgcn_mfma_f32_16x16x32_bf16(vf[nt][0], pf0.v, o[sub][nt], 0,0,0);
            o[sub][nt] = __builtin_amdgcn_mfma_f32_16x16x32_bf16(vf[nt][1], pf1.v, o[sub][nt], 0,0,0);
        }
        __builtin_amdgcn_s_setprio(0);
    }
}

__device__ __forceinline__ void attn_store(
    unsigned short* __restrict__ Y, const floatx4 o[2][4], const float l[2],
    int q0, int b, int h, int quad, int l16)
{
    float la = l[0], lb = l[1];
    la += __shfl_xor(la, 16); la += __shfl_xor(la, 32);
    lb += __shfl_xor(lb, 16); lb += __shfl_xor(lb, 32);
    const float ia = 1.0f / la, ib = 1.0f / lb;
    const size_t Rbase = (size_t)((b*NT + q0) >> 4);
    const int cg = (quad >> 1), co = (quad & 1)*4;
    #pragma unroll
    for (int nt = 0; nt < 4; ++nt) {
        const size_t base = ((Rbase*32 + h*2 + (nt >> 1))*512)
                          + (size_t)((((nt & 1)*2 + cg)*16 + l16)*8 + co);
        ushort4 wa, wb;
        wa.x = f2bf(o[0][nt][0]*ia); wa.y = f2bf(o[0][nt][1]*ia);
        wa.z = f2bf(o[0][nt][2]*ia); wa.w = f2bf(o[0][nt][3]*ia);
        wb.x = f2bf(o[1][nt][0]*ib); wb.y = f2bf(o[1][nt][1]*ib);
        wb.z = f2bf(o[1][nt][2]*ib); wb.w = f2bf(o[1][nt][3]*ib);
        *(ushort4*)&Y[base]         = wa;
        *(ushort4*)&Y[base + 16384] = wb;   // +1 row-tile (32*512)
    }
}

__device__ __forceinline__ void attn_pair(
    const unsigned short* __restrict__ Qf,
    const unsigned short* __restrict__ Kf,
    const unsigned short* __restrict__ Vf,
    unsigned short* __restrict__ Y,
    int bh, int stA, int stB, int lane)
{
    const int quad = lane >> 4, l16 = lane & 15;
    const int b = bh >> 4, h = bh & (NH - 1);
    const int q0A = stA * 32, q0B = stB * 32;
    const int FA = q0A >> 6, FB = q0B >> 6;    // FA < FB always (stA<32<=stB)

    const size_t qbA = ((size_t)(bh*128 + stA*2))*1024 + (size_t)lane*8;
    const size_t qbB = ((size_t)(bh*128 + stB*2))*1024 + (size_t)lane*8;
    bf16x8 qA[4], qB[4];
    qA[0] = *(const bf16x8*)&Qf[qbA];
    qA[1] = *(const bf16x8*)&Qf[qbA + 512];
    qA[2] = *(const bf16x8*)&Qf[qbA + 1024];
    qA[3] = *(const bf16x8*)&Qf[qbA + 1536];
    qB[0] = *(const bf16x8*)&Qf[qbB];
    qB[1] = *(const bf16x8*)&Qf[qbB + 512];
    qB[2] = *(const bf16x8*)&Qf[qbB + 1024];
    qB[3] = *(const bf16x8*)&Qf[qbB + 1536];

    const unsigned short* kp = Kf + (size_t)bh*131072 + (size_t)lane*8;
    const unsigned short* vp = Vf + (size_t)bh*131072 + (size_t)lane*8;

    floatx4 oA[2][4], oB[2][4];
    float lA[2] = {0.f, 0.f}, lB[2] = {0.f, 0.f};
    #pragma unroll
    for (int s2 = 0; s2 < 2; ++s2)
        #pragma unroll
        for (int nt = 0; nt < 4; ++nt) {
            oA[s2][nt] = (floatx4){0.f,0.f,0.f,0.f};
            oB[s2][nt] = (floatx4){0.f,0.f,0.f,0.f};
        }

    for (int f = 0; f <= FB; ++f) {
        const int j0 = f * 64;
        bf16x8 kf[4][2], vf[4][2];
        const unsigned short* kt = kp + (size_t)f * 4096;
        #pragma unroll
        for (int ct = 0; ct < 4; ++ct) {
            kf[ct][0] = *(const bf16x8*)&kt[ct*1024];
            kf[ct][1] = *(const bf16x8*)&kt[ct*1024 + 512];
        }
        const unsigned short* vt = vp + (size_t)f * 4096;
        #pragma unroll
        for (int nt = 0; nt < 4; ++nt) {
            vf[nt][0] = *(const bf16x8*)&vt[nt*512];
            vf[nt][1] = *(const bf16x8*)&vt[2048 + nt*512];
        }

        if (f <= FA)
            attn_tile(kf, vf, qA, oA, lA, f == FA, q0A, j0, quad, l16);
        attn_tile(kf, vf, qB, oB, lB, f == FB, q0B, j0, quad, l16);
    }

    attn_store(Y, oA, lA, q0A, b, h, quad, l16);
    attn_store(Y, oB, lB, q0B, b, h, quad, l16);
}

// T1 XCD-grouping: 512 blocks, 1-D. bh depends only on L mod 64 so all 8
// blocks of one (b,h) share L%8 (= XCD): each XCD serves 8 heads' K/V
// (4MB) from its own L2.
__global__ __launch_bounds__(256, 2) void flash_attn(
    const unsigned short* __restrict__ Qf,
    const unsigned short* __restrict__ Kf,
    const unsigned short* __restrict__ Vf,
    unsigned short* __restrict__ Y)
{
    const int tid  = threadIdx.x;
    const int wave = tid >> 6;
    const int lane = tid & 63;
    const int L  = blockIdx.x;
    const int bh = (L & 7) * 8 + ((L >> 3) & 7);
    const int x  = L >> 6;
    const int w  = x * 4 + wave;   // 0..31
    attn_pair(Qf, Kf, Vf, Y, bh, w, 63 - w, lane);
}

// ---------------- launch ----------------
extern "C" void kernel_launch(void* const* d_in, const int* in_sizes, int n_in,
                              void* d_out, int out_size, void* d_ws, size_t ws_size,
                              hipStream_t stream) {
    const float* x  = (const float*)d_in[0];
    const float* Wq = (const float*)d_in[1];
    const float* bq = (const float*)d_in[2];
    const float* Wk = (const float*)d_in[3];
    const float* bk = (const float*)d_in[4];
    const float* Wv = (const float*)d_in[5];
    const float* bv = (const float*)d_in[6];
    const float* Wo = (const float*)d_in[7];
    const float* bo = (const float*)d_in[8];

    char* ws = (char*)d_ws;
    size_t off = 0;
    auto alloc = [&](size_t bytes) -> void* {
        void* p = ws + off;
        off += (bytes + 255) & ~(size_t)255;
        return p;
    };
    unsigned short* xb  = (unsigned short*)alloc((size_t)NM * NC * 2);
    unsigned short* Wqb = (unsigned short*)alloc((size_t)NC * NC * 2);
    unsigned short* Wkb = (unsigned short*)alloc((size_t)NC * NC * 2);
    unsigned short* Wvb = (unsigned short*)alloc((size_t)NC * NC * 2);
    unsigned short* Wob = (unsigned short*)alloc((size_t)NC * NC * 2);
    unsigned short* Qb  = (unsigned short*)alloc((size_t)NM * NC * 2);
    unsigned short* Kb  = (unsigned short*)alloc((size_t)NM * NC * 2);
    unsigned short* Vtb = (unsigned short*)alloc((size_t)NM * NC * 2);
    unsigned short* Yb  = (unsigned short*)alloc((size_t)NM * NC * 2);

    const int ntx = NM * NC / 512;   // 16384 tiles
    const int ntw = NC * NC / 512;   // 2048 tiles per weight
    cast_x_tiled<<<(ntx*64 + 255)/256, 256, 0, stream>>>(x, xb, ntx);
    cast4_tiled<<<dim3((ntw*64 + 255)/256, 4), 256, 0, stream>>>(
        Wq, Wk, Wv, Wo, Wqb, Wkb, Wvb, Wob, ntw);

    gemm_qkv<<<dim3(NM / TM, 24), 256, 0, stream>>>(
        xb, Wqb, Wkb, Wvb, bq, bk, bv, Qb, Kb, Vtb);

    flash_attn<<<dim3(512), 256, 0, stream>>>(Qb, Kb, Vtb, Yb);

    gemm_out<<<dim3(NM / TM, NC / TN), 256, 0, stream>>>(Yb, Wob, bo, (float*)d_out);
}

// Round 4
// 233.753 us; speedup vs baseline: 1.1119x; 1.0007x over previous
//
#include <hip/hip_runtime.h>
#include <hip/hip_bf16.h>
#include <stdint.h>

// Problem constants
#define NB 4
#define NT 2048
#define NC 1024
#define NH 16
#define NHD 64
#define NM (NB*NT)   // 8192 rows

typedef __attribute__((ext_vector_type(8))) __bf16 bf16x8;
typedef __attribute__((ext_vector_type(4))) float floatx4;
typedef __attribute__((ext_vector_type(8))) unsigned short ushortx8;

#define AS1(p) ((const __attribute__((address_space(1))) void*)(p))
#define AS3(p) ((__attribute__((address_space(3))) void*)(p))

__device__ __forceinline__ unsigned short f2bf(float f) {
    union { float f; unsigned int u; } v; v.f = f;
    unsigned int u = v.u;
    return (unsigned short)((u + 0x7FFFu + ((u >> 16) & 1u)) >> 16);
}
// pack two fp32 -> (bf16(hi)<<16)|bf16(lo), RTZ, single v_perm_b32
__device__ __forceinline__ unsigned int pk2(float lo, float hi) {
    union { float f; unsigned int u; } a, b; a.f = hi; b.f = lo;
    return __builtin_amdgcn_perm(a.u, b.u, 0x07060302u);
}

// ===== fragment-tiled layout (for all GEMM operands) =====
// matrix (rows x 1024 cols) stored as 16x32 tiles of 512 shorts:
//   tile (R=row/16, C=col/32) at offset (R*32 + C)*512
//   element (r=row&15, c=col&31) at ((c>>3)*16 + r)*8 + (c&7)

// ---------------- merged cast fp32 -> bf16, fragment-tiled ------------------
// One launch covers x (16384 tiles) + 4 weights (2048 tiles each): removes a
// serialized kernel launch + tail imbalance vs the old two-kernel split.
__global__ void cast_all(const float* __restrict__ x,
                         const float* __restrict__ w0, const float* __restrict__ w1,
                         const float* __restrict__ w2, const float* __restrict__ w3,
                         unsigned short* __restrict__ xo,
                         unsigned short* __restrict__ o0, unsigned short* __restrict__ o1,
                         unsigned short* __restrict__ o2, unsigned short* __restrict__ o3)
{
    const int wid  = (blockIdx.x * blockDim.x + threadIdx.x) >> 6;
    const int lane = threadIdx.x & 63;
    const float* in; unsigned short* out; int tile;
    if (wid < 16384) { in = x; out = xo; tile = wid; }
    else {
        const int t = wid - 16384;
        tile = t & 2047;
        switch (t >> 11) {
            case 0: in = w0; out = o0; break;
            case 1: in = w1; out = o1; break;
            case 2: in = w2; out = o2; break;
            default: in = w3; out = o3; break;
        }
    }
    const int R = tile >> 5, C = tile & 31;
    const float* src = in + ((size_t)(R*16 + (lane >> 2)))*1024 + C*32 + (lane & 3)*8;
    const floatx4 v0 = *(const floatx4*)src;
    const floatx4 v1 = *(const floatx4*)(src + 4);
    ushortx8 o;
    o[0] = f2bf(v0[0]); o[1] = f2bf(v0[1]); o[2] = f2bf(v0[2]); o[3] = f2bf(v0[3]);
    o[4] = f2bf(v1[0]); o[5] = f2bf(v1[1]); o[6] = f2bf(v1[2]); o[7] = f2bf(v1[3]);
    *(ushortx8*)&out[(size_t)tile*512 + (((lane & 3)*16 + (lane >> 2)))*8] = o;
}

// ---------------- GEMM core: Out = (A @ W^T + bias) * oscale ----------------
// A, W fragment-tiled, K=1024. BK=32, 128x128 tile, 4 waves.
// R4: DOUBLE-BUFFERED LDS (2x16KB = 32KB, still ~5 blocks/CU) with raw
// s_barrier + counted vmcnt(4): the per-iteration vmcnt(0) drain that
// __syncthreads forced (the ~50% wait in R3's counters) is gone — the 4
// next-tile global_load_lds stay in flight across both barriers (T4).
// Hazards: stage(k+1) writes buf^1, first read only after the end-of-compute
// barrier of iter k-1; per-wave vmcnt(4)+barrier => tile k fully in LDS.
// MODE 0: Out fp32 row-major MxN (final projection)          [mfma(X, W)]
// MODE 1: Out bf16 Q/K fragment order, swapped operands      [mfma(W, X)]
// MODE 2: Out bf16 V^T key-permuted A-frag order             [mfma(X, W)]
// NOTE (R1): 256x256/128KB-LDS 8-phase rewrite regressed (1 block/CU killed
// m114 inter-block overlap). Keep 128x128 + small LDS.
#define TM 128
#define TN 128
#define BK 32

template<int MODE>
__device__ __forceinline__ void gemm_core(
    const unsigned short* __restrict__ A,
    const unsigned short* __restrict__ W,
    const float* __restrict__ bias,
    void* __restrict__ Out,
    unsigned short* As, unsigned short* Bs,   // each 2 x 4096 shorts (dbuf)
    int m_base, int n_base, float oscale)
{
    const int tid  = threadIdx.x;
    const int lane = tid & 63;
    const int wv   = tid >> 6;
    const int quad = lane >> 4;
    const int l16  = lane & 15;
    const int wm = (wv >> 1) * 64;
    const int wn = (wv & 1) * 64;

    floatx4 acc[4][4];
    #pragma unroll
    for (int i = 0; i < 4; ++i)
        #pragma unroll
        for (int j = 0; j < 4; ++j)
            acc[i][j] = (floatx4){0.f, 0.f, 0.f, 0.f};

    const int kct = NC >> 5;   // 32 k-tiles

    const unsigned short* At = A + ((size_t)((m_base >> 4) + wv*2) * kct) * 512 + (size_t)lane*8;
    const unsigned short* Wt = W + ((size_t)((n_base >> 4) + wv*2) * kct) * 512 + (size_t)lane*8;
    const size_t rstride = (size_t)kct * 512;

    // prologue: stage k-tile 0 into buf 0 (4 loads per wave)
    #pragma unroll
    for (int i = 0; i < 2; ++i) {
        __builtin_amdgcn_global_load_lds(AS1(At + i*rstride),
                                         AS3(&As[(wv*2 + i)*512]), 16, 0, 0);
        __builtin_amdgcn_global_load_lds(AS1(Wt + i*rstride),
                                         AS3(&Bs[(wv*2 + i)*512]), 16, 0, 0);
    }

    #pragma unroll 1
    for (int kt = 0; kt < 32; ++kt) {
        const int cur = (kt & 1) << 12;        // 0 / 4096 shorts
        const int nxt = 4096 - cur;
        if (kt < 31) {
            #pragma unroll
            for (int i = 0; i < 2; ++i) {
                __builtin_amdgcn_global_load_lds(
                    AS1(At + (size_t)(kt+1)*512 + i*rstride),
                    AS3(&As[nxt + (wv*2 + i)*512]), 16, 0, 0);
                __builtin_amdgcn_global_load_lds(
                    AS1(Wt + (size_t)(kt+1)*512 + i*rstride),
                    AS3(&Bs[nxt + (wv*2 + i)*512]), 16, 0, 0);
            }
            // own 4 newest (tile kt+1) stay in flight; tile kt's 4 are done
            asm volatile("s_waitcnt vmcnt(4)" ::: "memory");
        } else {
            asm volatile("s_waitcnt vmcnt(0)" ::: "memory");
        }
        __builtin_amdgcn_s_barrier();          // tile kt ready in buf cur

        bf16x8 af[4], bfr[4];
        #pragma unroll
        for (int mi = 0; mi < 4; ++mi)
            af[mi] = *(const bf16x8*)&As[cur + ((wv >> 1)*4 + mi)*512 + lane*8];
        #pragma unroll
        for (int ni = 0; ni < 4; ++ni)
            bfr[ni] = *(const bf16x8*)&Bs[cur + ((wv & 1)*4 + ni)*512 + lane*8];

        #pragma unroll
        for (int mi = 0; mi < 4; ++mi)
            #pragma unroll
            for (int ni = 0; ni < 4; ++ni) {
                if (MODE == 1)   // swapped: d on quad axis, t on l16
                    acc[mi][ni] = __builtin_amdgcn_mfma_f32_16x16x32_bf16(
                        bfr[ni], af[mi], acc[mi][ni], 0, 0, 0);
                else
                    acc[mi][ni] = __builtin_amdgcn_mfma_f32_16x16x32_bf16(
                        af[mi], bfr[ni], acc[mi][ni], 0, 0, 0);
            }
        __builtin_amdgcn_s_barrier();          // all waves done reading buf cur
    }

    // epilogue
    #pragma unroll
    for (int mi = 0; mi < 4; ++mi) {
        #pragma unroll
        for (int ni = 0; ni < 4; ++ni) {
            if (MODE == 0) {
                const int col = n_base + wn + ni*16 + l16;
                const float bv = bias[col & 1023];
                #pragma unroll
                for (int r = 0; r < 4; ++r) {
                    const int row = m_base + wm + mi*16 + quad*4 + r;
                    ((float*)Out)[(size_t)row * NC + col] =
                        (acc[mi][ni][r] + bv) * oscale;
                }
            } else if (MODE == 1) {
                const int d0 = n_base + wn + ni*16 + quad*4;
                const int t  = m_base + wm + mi*16 + l16;
                const float4 b4 = *(const float4*)&bias[d0];
                const int bb = t >> 11, tt = t & (NT - 1);
                const int h  = (d0 >> 6) & (NH - 1), dd0 = d0 & 63;
                const int bh = bb * NH + h;
                const size_t idx0 =
                    ((size_t)((bh*128 + (tt >> 4))*2 + (dd0 >> 5)))*512
                    + (size_t)((((dd0 >> 3) & 3)*16 + (tt & 15))*8 + (dd0 & 7));
                ushort4 st;
                st.x = f2bf((acc[mi][ni][0] + b4.x) * oscale);
                st.y = f2bf((acc[mi][ni][1] + b4.y) * oscale);
                st.z = f2bf((acc[mi][ni][2] + b4.z) * oscale);
                st.w = f2bf((acc[mi][ni][3] + b4.w) * oscale);
                *(ushort4*)&((unsigned short*)Out)[idx0] = st;
            } else {
                const int col = n_base + wn + ni*16 + l16;
                const float bv = bias[col & 1023];
                const int row0 = m_base + wm + mi*16 + quad*4;
                const int bb = row0 >> 11, t0 = row0 & (NT - 1);
                const int h  = (col >> 6) & (NH - 1), hd = col & 63;
                const int bh = bb * NH + h;
                const int tk0 = t0 & 31;
                const int qv  = (tk0 >> 2) & 3;
                const int jv0 = (tk0 >> 4) << 2;      // tk0&3 == 0
                const size_t idx0 =
                    ((size_t)((bh*64 + (t0 >> 5))*4 + (hd >> 4)))*512
                    + (size_t)((qv*16 + (hd & 15))*8 + jv0);
                ushort4 st;
                st.x = f2bf((acc[mi][ni][0] + bv) * oscale);
                st.y = f2bf((acc[mi][ni][1] + bv) * oscale);
                st.z = f2bf((acc[mi][ni][2] + bv) * oscale);
                st.w = f2bf((acc[mi][ni][3] + bv) * oscale);
                *(ushort4*)&((unsigned short*)Out)[idx0] = st;
            }
        }
    }
}

// Fused QKV: grid (64, 24); blockIdx.y: 0-7 Q, 8-15 K, 16-23 V
#define QSCALE (0.03125f * 1.44269504088896340736f)   // (1/sqrt(C)) * log2(e)

__global__ __launch_bounds__(256) void gemm_qkv(
    const unsigned short* __restrict__ A,
    const unsigned short* __restrict__ Wq, const unsigned short* __restrict__ Wk,
    const unsigned short* __restrict__ Wv,
    const float* __restrict__ bq, const float* __restrict__ bk,
    const float* __restrict__ bv,
    unsigned short* __restrict__ Qo, unsigned short* __restrict__ Ko,
    unsigned short* __restrict__ Vo)
{
    __shared__ __align__(16) unsigned short As[2*TM*BK];
    __shared__ __align__(16) unsigned short Bs[2*TN*BK];
    const int wi = blockIdx.y >> 3;
    const int n_base = (blockIdx.y & 7) * TN;
    const int m_base = blockIdx.x * TM;
    if (wi == 0)
        gemm_core<1>(A, Wq, bq, Qo, As, Bs, m_base, n_base, QSCALE);
    else if (wi == 1)
        gemm_core<1>(A, Wk, bk, Ko, As, Bs, m_base, n_base, 1.0f);
    else
        gemm_core<2>(A, Wv, bv, Vo, As, Bs, m_base, n_base, 1.0f);
}

__global__ __launch_bounds__(256) void gemm_out(
    const unsigned short* __restrict__ A,
    const unsigned short* __restrict__ W,
    const float* __restrict__ bias,
    float* __restrict__ Out)
{
    __shared__ __align__(16) unsigned short As[2*TM*BK];
    __shared__ __align__(16) unsigned short Bs[2*TN*BK];
    gemm_core<0>(A, W, bias, Out, As, Bs, blockIdx.x * TM, blockIdx.y * TN, 1.0f);
}

// ---------------- flash attention (causal), transposed-P scheme -------------
// S^T = mfma(A=K, B=Q); C-layout of S^T: l16 = Q-row, quad*4+r = key.
// exp -> P^T; pack pairs (v_perm RTZ) into B-operand of O^T = mfma(V^T, P^T).
// No LDS. T5 setprio around MFMA clusters (m191). Strip-pair fusion (R3).
// R4: skiphi — for an EVEN strip (q0%64==0) the diagonal tile's upper 32
// keys are fully masked: skip their QK MFMA, exp, pack and PV MFMA (8 of 16
// MFMA on that tile). Each wave-pair has exactly one even strip -> balanced.
__device__ __forceinline__ void attn_tile(
    const bf16x8 kf[4][2], const bf16x8 vf[4][2],
    const bf16x8 q[4], floatx4 o[2][4], float l[2],
    bool diag, bool skiphi, int q0, int j0, int quad, int l16)
{
    #pragma unroll
    for (int sub = 0; sub < 2; ++sub) {
        const bf16x8 qx0 = q[sub*2];
        const bf16x8 qx1 = q[sub*2 + 1];

        floatx4 s[4];
        __builtin_amdgcn_s_setprio(1);
        #pragma unroll
        for (int ct = 0; ct < 2; ++ct) {
            s[ct] = (floatx4){0.f,0.f,0.f,0.f};
            s[ct] = __builtin_amdgcn_mfma_f32_16x16x32_bf16(kf[ct][0], qx0, s[ct], 0,0,0);
            s[ct] = __builtin_amdgcn_mfma_f32_16x16x32_bf16(kf[ct][1], qx1, s[ct], 0,0,0);
        }
        if (!skiphi) {
            #pragma unroll
            for (int ct = 2; ct < 4; ++ct) {
                s[ct] = (floatx4){0.f,0.f,0.f,0.f};
                s[ct] = __builtin_amdgcn_mfma_f32_16x16x32_bf16(kf[ct][0], qx0, s[ct], 0,0,0);
                s[ct] = __builtin_amdgcn_mfma_f32_16x16x32_bf16(kf[ct][1], qx1, s[ct], 0,0,0);
            }
        }
        __builtin_amdgcn_s_setprio(0);

        float p[4][4];
        float lsum = 0.f;
        const int row = q0 + sub*16 + l16;
        if (!diag) {
            #pragma unroll
            for (int ct = 0; ct < 2; ++ct)
                #pragma unroll
                for (int r = 0; r < 4; ++r) {
                    p[ct][r] = __builtin_amdgcn_exp2f(s[ct][r]);
                    lsum += p[ct][r];
                }
        } else {
            #pragma unroll
            for (int ct = 0; ct < 2; ++ct)
                #pragma unroll
                for (int r = 0; r < 4; ++r) {
                    const int key = j0 + ct*16 + quad*4 + r;
                    p[ct][r] = (key <= row) ? __builtin_amdgcn_exp2f(s[ct][r]) : 0.f;
                    lsum += p[ct][r];
                }
        }
        if (!skiphi) {
            if (!diag) {
                #pragma unroll
                for (int ct = 2; ct < 4; ++ct)
                    #pragma unroll
                    for (int r = 0; r < 4; ++r) {
                        p[ct][r] = __builtin_amdgcn_exp2f(s[ct][r]);
                        lsum += p[ct][r];
                    }
            } else {
                #pragma unroll
                for (int ct = 2; ct < 4; ++ct)
                    #pragma unroll
                    for (int r = 0; r < 4; ++r) {
                        const int key = j0 + ct*16 + quad*4 + r;
                        p[ct][r] = (key <= row) ? __builtin_amdgcn_exp2f(s[ct][r]) : 0.f;
                        lsum += p[ct][r];
                    }
            }
        }
        l[sub] += lsum;

        union { bf16x8 v; unsigned int u[4]; } pf0;
        pf0.u[0] = pk2(p[0][0], p[0][1]); pf0.u[1] = pk2(p[0][2], p[0][3]);
        pf0.u[2] = pk2(p[1][0], p[1][1]); pf0.u[3] = pk2(p[1][2], p[1][3]);

        __builtin_amdgcn_s_setprio(1);
        #pragma unroll
        for (int nt = 0; nt < 4; ++nt)
            o[sub][nt] = __builtin_amdgcn_mfma_f32_16x16x32_bf16(vf[nt][0], pf0.v, o[sub][nt], 0,0,0);
        __builtin_amdgcn_s_setprio(0);

        if (!skiphi) {
            union { bf16x8 v; unsigned int u[4]; } pf1;
            pf1.u[0] = pk2(p[2][0], p[2][1]); pf1.u[1] = pk2(p[2][2], p[2][3]);
            pf1.u[2] = pk2(p[3][0], p[3][1]); pf1.u[3] = pk2(p[3][2], p[3][3]);
            __builtin_amdgcn_s_setprio(1);
            #pragma unroll
            for (int nt = 0; nt < 4; ++nt)
                o[sub][nt] = __builtin_amdgcn_mfma_f32_16x16x32_bf16(vf[nt][1], pf1.v, o[sub][nt], 0,0,0);
            __builtin_amdgcn_s_setprio(0);
        }
    }
}

__device__ __forceinline__ void attn_store(
    unsigned short* __restrict__ Y, const floatx4 o[2][4], const float l[2],
    int q0, int b, int h, int quad, int l16)
{
    float la = l[0], lb = l[1];
    la += __shfl_xor(la, 16); la += __shfl_xor(la, 32);
    lb += __shfl_xor(lb, 16); lb += __shfl_xor(lb, 32);
    const float ia = 1.0f / la, ib = 1.0f / lb;
    const size_t Rbase = (size_t)((b*NT + q0) >> 4);
    const int cg = (quad >> 1), co = (quad & 1)*4;
    #pragma unroll
    for (int nt = 0; nt < 4; ++nt) {
        const size_t base = ((Rbase*32 + h*2 + (nt >> 1))*512)
                          + (size_t)((((nt & 1)*2 + cg)*16 + l16)*8 + co);
        ushort4 wa, wb;
        wa.x = f2bf(o[0][nt][0]*ia); wa.y = f2bf(o[0][nt][1]*ia);
        wa.z = f2bf(o[0][nt][2]*ia); wa.w = f2bf(o[0][nt][3]*ia);
        wb.x = f2bf(o[1][nt][0]*ib); wb.y = f2bf(o[1][nt][1]*ib);
        wb.z = f2bf(o[1][nt][2]*ib); wb.w = f2bf(o[1][nt][3]*ib);
        *(ushort4*)&Y[base]         = wa;
        *(ushort4*)&Y[base + 16384] = wb;   // +1 row-tile (32*512)
    }
}

__device__ __forceinline__ void attn_pair(
    const unsigned short* __restrict__ Qf,
    const unsigned short* __restrict__ Kf,
    const unsigned short* __restrict__ Vf,
    unsigned short* __restrict__ Y,
    int bh, int stA, int stB, int lane)
{
    const int quad = lane >> 4, l16 = lane & 15;
    const int b = bh >> 4, h = bh & (NH - 1);
    const int q0A = stA * 32, q0B = stB * 32;
    const int FA = q0A >> 6, FB = q0B >> 6;    // FA < FB always (stA<32<=stB)
    const bool skA = (q0A & 32) == 0;          // even strip: diag upper half dead
    const bool skB = (q0B & 32) == 0;

    const size_t qbA = ((size_t)(bh*128 + stA*2))*1024 + (size_t)lane*8;
    const size_t qbB = ((size_t)(bh*128 + stB*2))*1024 + (size_t)lane*8;
    bf16x8 qA[4], qB[4];
    qA[0] = *(const bf16x8*)&Qf[qbA];
    qA[1] = *(const bf16x8*)&Qf[qbA + 512];
    qA[2] = *(const bf16x8*)&Qf[qbA + 1024];
    qA[3] = *(const bf16x8*)&Qf[qbA + 1536];
    qB[0] = *(const bf16x8*)&Qf[qbB];
    qB[1] = *(const bf16x8*)&Qf[qbB + 512];
    qB[2] = *(const bf16x8*)&Qf[qbB + 1024];
    qB[3] = *(const bf16x8*)&Qf[qbB + 1536];

    const unsigned short* kp = Kf + (size_t)bh*131072 + (size_t)lane*8;
    const unsigned short* vp = Vf + (size_t)bh*131072 + (size_t)lane*8;

    floatx4 oA[2][4], oB[2][4];
    float lA[2] = {0.f, 0.f}, lB[2] = {0.f, 0.f};
    #pragma unroll
    for (int s2 = 0; s2 < 2; ++s2)
        #pragma unroll
        for (int nt = 0; nt < 4; ++nt) {
            oA[s2][nt] = (floatx4){0.f,0.f,0.f,0.f};
            oB[s2][nt] = (floatx4){0.f,0.f,0.f,0.f};
        }

    for (int f = 0; f <= FB; ++f) {
        const int j0 = f * 64;
        bf16x8 kf[4][2], vf[4][2];
        const unsigned short* kt = kp + (size_t)f * 4096;
        #pragma unroll
        for (int ct = 0; ct < 4; ++ct) {
            kf[ct][0] = *(const bf16x8*)&kt[ct*1024];
            kf[ct][1] = *(const bf16x8*)&kt[ct*1024 + 512];
        }
        const unsigned short* vt = vp + (size_t)f * 4096;
        #pragma unroll
        for (int nt = 0; nt < 4; ++nt) {
            vf[nt][0] = *(const bf16x8*)&vt[nt*512];
            vf[nt][1] = *(const bf16x8*)&vt[2048 + nt*512];
        }

        if (f <= FA)
            attn_tile(kf, vf, qA, oA, lA, f == FA, (f == FA) && skA,
                      q0A, j0, quad, l16);
        attn_tile(kf, vf, qB, oB, lB, f == FB, (f == FB) && skB,
                  q0B, j0, quad, l16);
    }

    attn_store(Y, oA, lA, q0A, b, h, quad, l16);
    attn_store(Y, oB, lB, q0B, b, h, quad, l16);
}

// T1 XCD-grouping: 512 blocks, 1-D. bh depends only on L mod 64 so all 8
// blocks of one (b,h) share L%8 (= XCD): each XCD serves 8 heads' K/V
// (4MB) from its own L2.
__global__ __launch_bounds__(256, 2) void flash_attn(
    const unsigned short* __restrict__ Qf,
    const unsigned short* __restrict__ Kf,
    const unsigned short* __restrict__ Vf,
    unsigned short* __restrict__ Y)
{
    const int tid  = threadIdx.x;
    const int wave = tid >> 6;
    const int lane = tid & 63;
    const int L  = blockIdx.x;
    const int bh = (L & 7) * 8 + ((L >> 3) & 7);
    const int x  = L >> 6;
    const int w  = x * 4 + wave;   // 0..31
    attn_pair(Qf, Kf, Vf, Y, bh, w, 63 - w, lane);
}

// ---------------- launch ----------------
extern "C" void kernel_launch(void* const* d_in, const int* in_sizes, int n_in,
                              void* d_out, int out_size, void* d_ws, size_t ws_size,
                              hipStream_t stream) {
    const float* x  = (const float*)d_in[0];
    const float* Wq = (const float*)d_in[1];
    const float* bq = (const float*)d_in[2];
    const float* Wk = (const float*)d_in[3];
    const float* bk = (const float*)d_in[4];
    const float* Wv = (const float*)d_in[5];
    const float* bv = (const float*)d_in[6];
    const float* Wo = (const float*)d_in[7];
    const float* bo = (const float*)d_in[8];

    char* ws = (char*)d_ws;
    size_t off = 0;
    auto alloc = [&](size_t bytes) -> void* {
        void* p = ws + off;
        off += (bytes + 255) & ~(size_t)255;
        return p;
    };
    unsigned short* xb  = (unsigned short*)alloc((size_t)NM * NC * 2);
    unsigned short* Wqb = (unsigned short*)alloc((size_t)NC * NC * 2);
    unsigned short* Wkb = (unsigned short*)alloc((size_t)NC * NC * 2);
    unsigned short* Wvb = (unsigned short*)alloc((size_t)NC * NC * 2);
    unsigned short* Wob = (unsigned short*)alloc((size_t)NC * NC * 2);
    unsigned short* Qb  = (unsigned short*)alloc((size_t)NM * NC * 2);
    unsigned short* Kb  = (unsigned short*)alloc((size_t)NM * NC * 2);
    unsigned short* Vtb = (unsigned short*)alloc((size_t)NM * NC * 2);
    unsigned short* Yb  = (unsigned short*)alloc((size_t)NM * NC * 2);

    // 16384 x-tiles + 4*2048 weight tiles = 24576 wave-tiles
    cast_all<<<(24576*64)/256, 256, 0, stream>>>(
        x, Wq, Wk, Wv, Wo, xb, Wqb, Wkb, Wvb, Wob);

    gemm_qkv<<<dim3(NM / TM, 24), 256, 0, stream>>>(
        xb, Wqb, Wkb, Wvb, bq, bk, bv, Qb, Kb, Vtb);

    flash_attn<<<dim3(512), 256, 0, stream>>>(Qb, Kb, Vtb, Yb);

    gemm_out<<<dim3(NM / TM, NC / TN), 256, 0, stream>>>(Yb, Wob, bo, (float*)d_out);
}

// Round 5
// 233.431 us; speedup vs baseline: 1.1134x; 1.0014x over previous
//
#include <hip/hip_runtime.h>
#include <hip/hip_bf16.h>
#include <stdint.h>

// Problem constants
#define NB 4
#define NT 2048
#define NC 1024
#define NH 16
#define NHD 64
#define NM (NB*NT)   // 8192 rows

typedef __attribute__((ext_vector_type(8))) __bf16 bf16x8;
typedef __attribute__((ext_vector_type(4))) float floatx4;
typedef __attribute__((ext_vector_type(8))) unsigned short ushortx8;

#define AS1(p) ((const __attribute__((address_space(1))) void*)(p))
#define AS3(p) ((__attribute__((address_space(3))) void*)(p))

__device__ __forceinline__ unsigned short f2bf(float f) {
    union { float f; unsigned int u; } v; v.f = f;
    unsigned int u = v.u;
    return (unsigned short)((u + 0x7FFFu + ((u >> 16) & 1u)) >> 16);
}
// pack two fp32 -> (bf16(hi)<<16)|bf16(lo), RTZ, single v_perm_b32
__device__ __forceinline__ unsigned int pk2(float lo, float hi) {
    union { float f; unsigned int u; } a, b; a.f = hi; b.f = lo;
    return __builtin_amdgcn_perm(a.u, b.u, 0x07060302u);
}

// ===== fragment-tiled layout (for all GEMM operands) =====
// matrix (rows x 1024 cols) stored as 16x32 tiles of 512 shorts:
//   tile (R=row/16, C=col/32) at offset (R*32 + C)*512
//   element (r=row&15, c=col&31) at ((c>>3)*16 + r)*8 + (c&7)

// ---------------- merged cast fp32 -> bf16, fragment-tiled ------------------
__global__ void cast_all(const float* __restrict__ x,
                         const float* __restrict__ w0, const float* __restrict__ w1,
                         const float* __restrict__ w2, const float* __restrict__ w3,
                         unsigned short* __restrict__ xo,
                         unsigned short* __restrict__ o0, unsigned short* __restrict__ o1,
                         unsigned short* __restrict__ o2, unsigned short* __restrict__ o3)
{
    const int wid  = (blockIdx.x * blockDim.x + threadIdx.x) >> 6;
    const int lane = threadIdx.x & 63;
    const float* in; unsigned short* out; int tile;
    if (wid < 16384) { in = x; out = xo; tile = wid; }
    else {
        const int t = wid - 16384;
        tile = t & 2047;
        switch (t >> 11) {
            case 0: in = w0; out = o0; break;
            case 1: in = w1; out = o1; break;
            case 2: in = w2; out = o2; break;
            default: in = w3; out = o3; break;
        }
    }
    const int R = tile >> 5, C = tile & 31;
    const float* src = in + ((size_t)(R*16 + (lane >> 2)))*1024 + C*32 + (lane & 3)*8;
    const floatx4 v0 = *(const floatx4*)src;
    const floatx4 v1 = *(const floatx4*)(src + 4);
    ushortx8 o;
    o[0] = f2bf(v0[0]); o[1] = f2bf(v0[1]); o[2] = f2bf(v0[2]); o[3] = f2bf(v0[3]);
    o[4] = f2bf(v1[0]); o[5] = f2bf(v1[1]); o[6] = f2bf(v1[2]); o[7] = f2bf(v1[3]);
    *(ushortx8*)&out[(size_t)tile*512 + (((lane & 3)*16 + (lane >> 2)))*8] = o;
}

// ---------------- GEMM core: Out = (A @ W^T + bias) * oscale ----------------
// A, W fragment-tiled, K=1024. BK=32, 128x128 tile, 4 waves, dbuf 32KB LDS,
// raw s_barrier + counted vmcnt(4) (R4 — measured neutral vs sync, kept).
// R5 post-mortem chain: sync-16KB (R3) == swap-epilogue (R3) == dbuf-counted
// (R4) == 73.4us -> intra-loop schedule is NOT the limiter. Two-point fit vs
// m103 (same structure, K=4096, 912 TF) gives per-block fixed overhead
// F ~= 14 K-iters: at K=1024 that's ~30% of block time. R5 therefore merges
// the 3 QKV sub-GEMMs into one block (3 K-loops back-to-back, same LDS):
// same staging/MFMA work, F amortized 3x, grid 512 = 2.0 blocks/CU exact.
// MODE 0: Out fp32 row-major MxN (final projection)          [mfma(X, W)]
// MODE 1: Out bf16 Q/K fragment order, swapped operands      [mfma(W, X)]
// MODE 2: Out bf16 V^T key-permuted A-frag order             [mfma(X, W)]
// NOTE (R1): 256x256/128KB-LDS 8-phase rewrite regressed (1 block/CU killed
// m114 inter-block overlap). Keep 128x128 + small LDS.
#define TM 128
#define TN 128
#define BK 32

template<int MODE>
__device__ __forceinline__ void gemm_core(
    const unsigned short* __restrict__ A,
    const unsigned short* __restrict__ W,
    const float* __restrict__ bias,
    void* __restrict__ Out,
    unsigned short* As, unsigned short* Bs,   // each 2 x 4096 shorts (dbuf)
    int m_base, int n_base, float oscale)
{
    const int tid  = threadIdx.x;
    const int lane = tid & 63;
    const int wv   = tid >> 6;
    const int quad = lane >> 4;
    const int l16  = lane & 15;
    const int wm = (wv >> 1) * 64;
    const int wn = (wv & 1) * 64;

    floatx4 acc[4][4];
    #pragma unroll
    for (int i = 0; i < 4; ++i)
        #pragma unroll
        for (int j = 0; j < 4; ++j)
            acc[i][j] = (floatx4){0.f, 0.f, 0.f, 0.f};

    const int kct = NC >> 5;   // 32 k-tiles

    const unsigned short* At = A + ((size_t)((m_base >> 4) + wv*2) * kct) * 512 + (size_t)lane*8;
    const unsigned short* Wt = W + ((size_t)((n_base >> 4) + wv*2) * kct) * 512 + (size_t)lane*8;
    const size_t rstride = (size_t)kct * 512;

    // prologue: stage k-tile 0 into buf 0 (4 loads per wave)
    #pragma unroll
    for (int i = 0; i < 2; ++i) {
        __builtin_amdgcn_global_load_lds(AS1(At + i*rstride),
                                         AS3(&As[(wv*2 + i)*512]), 16, 0, 0);
        __builtin_amdgcn_global_load_lds(AS1(Wt + i*rstride),
                                         AS3(&Bs[(wv*2 + i)*512]), 16, 0, 0);
    }

    #pragma unroll 1
    for (int kt = 0; kt < 32; ++kt) {
        const int cur = (kt & 1) << 12;        // 0 / 4096 shorts
        const int nxt = 4096 - cur;
        if (kt < 31) {
            #pragma unroll
            for (int i = 0; i < 2; ++i) {
                __builtin_amdgcn_global_load_lds(
                    AS1(At + (size_t)(kt+1)*512 + i*rstride),
                    AS3(&As[nxt + (wv*2 + i)*512]), 16, 0, 0);
                __builtin_amdgcn_global_load_lds(
                    AS1(Wt + (size_t)(kt+1)*512 + i*rstride),
                    AS3(&Bs[nxt + (wv*2 + i)*512]), 16, 0, 0);
            }
            // own 4 newest (tile kt+1) stay in flight; tile kt's 4 are done
            asm volatile("s_waitcnt vmcnt(4)" ::: "memory");
        } else {
            asm volatile("s_waitcnt vmcnt(0)" ::: "memory");
        }
        __builtin_amdgcn_s_barrier();          // tile kt ready in buf cur

        bf16x8 af[4], bfr[4];
        #pragma unroll
        for (int mi = 0; mi < 4; ++mi)
            af[mi] = *(const bf16x8*)&As[cur + ((wv >> 1)*4 + mi)*512 + lane*8];
        #pragma unroll
        for (int ni = 0; ni < 4; ++ni)
            bfr[ni] = *(const bf16x8*)&Bs[cur + ((wv & 1)*4 + ni)*512 + lane*8];

        #pragma unroll
        for (int mi = 0; mi < 4; ++mi)
            #pragma unroll
            for (int ni = 0; ni < 4; ++ni) {
                if (MODE == 1)   // swapped: d on quad axis, t on l16
                    acc[mi][ni] = __builtin_amdgcn_mfma_f32_16x16x32_bf16(
                        bfr[ni], af[mi], acc[mi][ni], 0, 0, 0);
                else
                    acc[mi][ni] = __builtin_amdgcn_mfma_f32_16x16x32_bf16(
                        af[mi], bfr[ni], acc[mi][ni], 0, 0, 0);
            }
        __builtin_amdgcn_s_barrier();          // all waves done reading buf cur
    }

    // epilogue
    #pragma unroll
    for (int mi = 0; mi < 4; ++mi) {
        #pragma unroll
        for (int ni = 0; ni < 4; ++ni) {
            if (MODE == 0) {
                const int col = n_base + wn + ni*16 + l16;
                const float bv = bias[col & 1023];
                #pragma unroll
                for (int r = 0; r < 4; ++r) {
                    const int row = m_base + wm + mi*16 + quad*4 + r;
                    ((float*)Out)[(size_t)row * NC + col] =
                        (acc[mi][ni][r] + bv) * oscale;
                }
            } else if (MODE == 1) {
                const int d0 = n_base + wn + ni*16 + quad*4;
                const int t  = m_base + wm + mi*16 + l16;
                const float4 b4 = *(const float4*)&bias[d0];
                const int bb = t >> 11, tt = t & (NT - 1);
                const int h  = (d0 >> 6) & (NH - 1), dd0 = d0 & 63;
                const int bh = bb * NH + h;
                const size_t idx0 =
                    ((size_t)((bh*128 + (tt >> 4))*2 + (dd0 >> 5)))*512
                    + (size_t)((((dd0 >> 3) & 3)*16 + (tt & 15))*8 + (dd0 & 7));
                ushort4 st;
                st.x = f2bf((acc[mi][ni][0] + b4.x) * oscale);
                st.y = f2bf((acc[mi][ni][1] + b4.y) * oscale);
                st.z = f2bf((acc[mi][ni][2] + b4.z) * oscale);
                st.w = f2bf((acc[mi][ni][3] + b4.w) * oscale);
                *(ushort4*)&((unsigned short*)Out)[idx0] = st;
            } else {
                const int col = n_base + wn + ni*16 + l16;
                const float bv = bias[col & 1023];
                const int row0 = m_base + wm + mi*16 + quad*4;
                const int bb = row0 >> 11, t0 = row0 & (NT - 1);
                const int h  = (col >> 6) & (NH - 1), hd = col & 63;
                const int bh = bb * NH + h;
                const int tk0 = t0 & 31;
                const int qv  = (tk0 >> 2) & 3;
                const int jv0 = (tk0 >> 4) << 2;      // tk0&3 == 0
                const size_t idx0 =
                    ((size_t)((bh*64 + (t0 >> 5))*4 + (hd >> 4)))*512
                    + (size_t)((qv*16 + (hd & 15))*8 + jv0);
                ushort4 st;
                st.x = f2bf((acc[mi][ni][0] + bv) * oscale);
                st.y = f2bf((acc[mi][ni][1] + bv) * oscale);
                st.z = f2bf((acc[mi][ni][2] + bv) * oscale);
                st.w = f2bf((acc[mi][ni][3] + bv) * oscale);
                *(ushort4*)&((unsigned short*)Out)[idx0] = st;
            }
        }
    }
}

// R5 merged QKV: grid (64, 8). One block = 3 back-to-back sub-GEMMs (Q,K,V)
// over the same (m_base, n_base): F amortized 3x, 512 blocks = 2.0/CU exact.
// Inter-sub-GEMM safety: each K-loop ends with a full s_barrier after the
// last LDS read, so the next prologue's global_load_lds cannot race; the
// next K-loop's first vmcnt(4) also covers leftover epilogue stores.
#define QSCALE (0.03125f * 1.44269504088896340736f)   // (1/sqrt(C)) * log2(e)

__global__ __launch_bounds__(256) void gemm_qkv(
    const unsigned short* __restrict__ A,
    const unsigned short* __restrict__ Wq, const unsigned short* __restrict__ Wk,
    const unsigned short* __restrict__ Wv,
    const float* __restrict__ bq, const float* __restrict__ bk,
    const float* __restrict__ bv,
    unsigned short* __restrict__ Qo, unsigned short* __restrict__ Ko,
    unsigned short* __restrict__ Vo)
{
    __shared__ __align__(16) unsigned short As[2*TM*BK];
    __shared__ __align__(16) unsigned short Bs[2*TN*BK];
    const int m_base = blockIdx.x * TM;
    const int n_base = blockIdx.y * TN;
    gemm_core<1>(A, Wq, bq, Qo, As, Bs, m_base, n_base, QSCALE);
    gemm_core<1>(A, Wk, bk, Ko, As, Bs, m_base, n_base, 1.0f);
    gemm_core<2>(A, Wv, bv, Vo, As, Bs, m_base, n_base, 1.0f);
}

__global__ __launch_bounds__(256) void gemm_out(
    const unsigned short* __restrict__ A,
    const unsigned short* __restrict__ W,
    const float* __restrict__ bias,
    float* __restrict__ Out)
{
    __shared__ __align__(16) unsigned short As[2*TM*BK];
    __shared__ __align__(16) unsigned short Bs[2*TN*BK];
    gemm_core<0>(A, W, bias, Out, As, Bs, blockIdx.x * TM, blockIdx.y * TN, 1.0f);
}

// ---------------- flash attention (causal), transposed-P scheme -------------
// S^T = mfma(A=K, B=Q); C-layout of S^T: l16 = Q-row, quad*4+r = key.
// exp -> P^T; pack pairs (v_perm RTZ) into B-operand of O^T = mfma(V^T, P^T).
// No LDS. T5 setprio (m191). Strip-pair fusion (R3). Diag-half skip (R4).
// R5: lsum tree-reduce — per-ct 2-level tree then 4 accumulates (depth ~6
// vs 16 serial dependent FP adds).
__device__ __forceinline__ void attn_tile(
    const bf16x8 kf[4][2], const bf16x8 vf[4][2],
    const bf16x8 q[4], floatx4 o[2][4], float l[2],
    bool diag, bool skiphi, int q0, int j0, int quad, int l16)
{
    #pragma unroll
    for (int sub = 0; sub < 2; ++sub) {
        const bf16x8 qx0 = q[sub*2];
        const bf16x8 qx1 = q[sub*2 + 1];

        floatx4 s[4];
        __builtin_amdgcn_s_setprio(1);
        #pragma unroll
        for (int ct = 0; ct < 2; ++ct) {
            s[ct] = (floatx4){0.f,0.f,0.f,0.f};
            s[ct] = __builtin_amdgcn_mfma_f32_16x16x32_bf16(kf[ct][0], qx0, s[ct], 0,0,0);
            s[ct] = __builtin_amdgcn_mfma_f32_16x16x32_bf16(kf[ct][1], qx1, s[ct], 0,0,0);
        }
        if (!skiphi) {
            #pragma unroll
            for (int ct = 2; ct < 4; ++ct) {
                s[ct] = (floatx4){0.f,0.f,0.f,0.f};
                s[ct] = __builtin_amdgcn_mfma_f32_16x16x32_bf16(kf[ct][0], qx0, s[ct], 0,0,0);
                s[ct] = __builtin_amdgcn_mfma_f32_16x16x32_bf16(kf[ct][1], qx1, s[ct], 0,0,0);
            }
        }
        __builtin_amdgcn_s_setprio(0);

        float p[4][4];
        float psum[4];
        const int row = q0 + sub*16 + l16;
        #pragma unroll
        for (int ct = 0; ct < 2; ++ct) {
            if (!diag) {
                #pragma unroll
                for (int r = 0; r < 4; ++r)
                    p[ct][r] = __builtin_amdgcn_exp2f(s[ct][r]);
            } else {
                #pragma unroll
                for (int r = 0; r < 4; ++r) {
                    const int key = j0 + ct*16 + quad*4 + r;
                    p[ct][r] = (key <= row) ? __builtin_amdgcn_exp2f(s[ct][r]) : 0.f;
                }
            }
            psum[ct] = (p[ct][0] + p[ct][1]) + (p[ct][2] + p[ct][3]);
        }
        if (!skiphi) {
            #pragma unroll
            for (int ct = 2; ct < 4; ++ct) {
                if (!diag) {
                    #pragma unroll
                    for (int r = 0; r < 4; ++r)
                        p[ct][r] = __builtin_amdgcn_exp2f(s[ct][r]);
                } else {
                    #pragma unroll
                    for (int r = 0; r < 4; ++r) {
                        const int key = j0 + ct*16 + quad*4 + r;
                        p[ct][r] = (key <= row) ? __builtin_amdgcn_exp2f(s[ct][r]) : 0.f;
                    }
                }
                psum[ct] = (p[ct][0] + p[ct][1]) + (p[ct][2] + p[ct][3]);
            }
            l[sub] += (psum[0] + psum[1]) + (psum[2] + psum[3]);
        } else {
            l[sub] += psum[0] + psum[1];
        }

        union { bf16x8 v; unsigned int u[4]; } pf0;
        pf0.u[0] = pk2(p[0][0], p[0][1]); pf0.u[1] = pk2(p[0][2], p[0][3]);
        pf0.u[2] = pk2(p[1][0], p[1][1]); pf0.u[3] = pk2(p[1][2], p[1][3]);

        __builtin_amdgcn_s_setprio(1);
        #pragma unroll
        for (int nt = 0; nt < 4; ++nt)
            o[sub][nt] = __builtin_amdgcn_mfma_f32_16x16x32_bf16(vf[nt][0], pf0.v, o[sub][nt], 0,0,0);
        __builtin_amdgcn_s_setprio(0);

        if (!skiphi) {
            union { bf16x8 v; unsigned int u[4]; } pf1;
            pf1.u[0] = pk2(p[2][0], p[2][1]); pf1.u[1] = pk2(p[2][2], p[2][3]);
            pf1.u[2] = pk2(p[3][0], p[3][1]); pf1.u[3] = pk2(p[3][2], p[3][3]);
            __builtin_amdgcn_s_setprio(1);
            #pragma unroll
            for (int nt = 0; nt < 4; ++nt)
                o[sub][nt] = __builtin_amdgcn_mfma_f32_16x16x32_bf16(vf[nt][1], pf1.v, o[sub][nt], 0,0,0);
            __builtin_amdgcn_s_setprio(0);
        }
    }
}

__device__ __forceinline__ void attn_store(
    unsigned short* __restrict__ Y, const floatx4 o[2][4], const float l[2],
    int q0, int b, int h, int quad, int l16)
{
    float la = l[0], lb = l[1];
    la += __shfl_xor(la, 16); la += __shfl_xor(la, 32);
    lb += __shfl_xor(lb, 16); lb += __shfl_xor(lb, 32);
    const float ia = 1.0f / la, ib = 1.0f / lb;
    const size_t Rbase = (size_t)((b*NT + q0) >> 4);
    const int cg = (quad >> 1), co = (quad & 1)*4;
    #pragma unroll
    for (int nt = 0; nt < 4; ++nt) {
        const size_t base = ((Rbase*32 + h*2 + (nt >> 1))*512)
                          + (size_t)((((nt & 1)*2 + cg)*16 + l16)*8 + co);
        ushort4 wa, wb;
        wa.x = f2bf(o[0][nt][0]*ia); wa.y = f2bf(o[0][nt][1]*ia);
        wa.z = f2bf(o[0][nt][2]*ia); wa.w = f2bf(o[0][nt][3]*ia);
        wb.x = f2bf(o[1][nt][0]*ib); wb.y = f2bf(o[1][nt][1]*ib);
        wb.z = f2bf(o[1][nt][2]*ib); wb.w = f2bf(o[1][nt][3]*ib);
        *(ushort4*)&Y[base]         = wa;
        *(ushort4*)&Y[base + 16384] = wb;   // +1 row-tile (32*512)
    }
}

__device__ __forceinline__ void attn_pair(
    const unsigned short* __restrict__ Qf,
    const unsigned short* __restrict__ Kf,
    const unsigned short* __restrict__ Vf,
    unsigned short* __restrict__ Y,
    int bh, int stA, int stB, int lane)
{
    const int quad = lane >> 4, l16 = lane & 15;
    const int b = bh >> 4, h = bh & (NH - 1);
    const int q0A = stA * 32, q0B = stB * 32;
    const int FA = q0A >> 6, FB = q0B >> 6;    // FA < FB always (stA<32<=stB)
    const bool skA = (q0A & 32) == 0;          // even strip: diag upper half dead
    const bool skB = (q0B & 32) == 0;

    const size_t qbA = ((size_t)(bh*128 + stA*2))*1024 + (size_t)lane*8;
    const size_t qbB = ((size_t)(bh*128 + stB*2))*1024 + (size_t)lane*8;
    bf16x8 qA[4], qB[4];
    qA[0] = *(const bf16x8*)&Qf[qbA];
    qA[1] = *(const bf16x8*)&Qf[qbA + 512];
    qA[2] = *(const bf16x8*)&Qf[qbA + 1024];
    qA[3] = *(const bf16x8*)&Qf[qbA + 1536];
    qB[0] = *(const bf16x8*)&Qf[qbB];
    qB[1] = *(const bf16x8*)&Qf[qbB + 512];
    qB[2] = *(const bf16x8*)&Qf[qbB + 1024];
    qB[3] = *(const bf16x8*)&Qf[qbB + 1536];

    const unsigned short* kp = Kf + (size_t)bh*131072 + (size_t)lane*8;
    const unsigned short* vp = Vf + (size_t)bh*131072 + (size_t)lane*8;

    floatx4 oA[2][4], oB[2][4];
    float lA[2] = {0.f, 0.f}, lB[2] = {0.f, 0.f};
    #pragma unroll
    for (int s2 = 0; s2 < 2; ++s2)
        #pragma unroll
        for (int nt = 0; nt < 4; ++nt) {
            oA[s2][nt] = (floatx4){0.f,0.f,0.f,0.f};
            oB[s2][nt] = (floatx4){0.f,0.f,0.f,0.f};
        }

    for (int f = 0; f <= FB; ++f) {
        const int j0 = f * 64;
        bf16x8 kf[4][2], vf[4][2];
        const unsigned short* kt = kp + (size_t)f * 4096;
        #pragma unroll
        for (int ct = 0; ct < 4; ++ct) {
            kf[ct][0] = *(const bf16x8*)&kt[ct*1024];
            kf[ct][1] = *(const bf16x8*)&kt[ct*1024 + 512];
        }
        const unsigned short* vt = vp + (size_t)f * 4096;
        #pragma unroll
        for (int nt = 0; nt < 4; ++nt) {
            vf[nt][0] = *(const bf16x8*)&vt[nt*512];
            vf[nt][1] = *(const bf16x8*)&vt[2048 + nt*512];
        }

        if (f <= FA)
            attn_tile(kf, vf, qA, oA, lA, f == FA, (f == FA) && skA,
                      q0A, j0, quad, l16);
        attn_tile(kf, vf, qB, oB, lB, f == FB, (f == FB) && skB,
                  q0B, j0, quad, l16);
    }

    attn_store(Y, oA, lA, q0A, b, h, quad, l16);
    attn_store(Y, oB, lB, q0B, b, h, quad, l16);
}

// T1 XCD-grouping: 512 blocks, 1-D. bh depends only on L mod 64 so all 8
// blocks of one (b,h) share L%8 (= XCD): each XCD serves 8 heads' K/V
// (4MB) from its own L2.
__global__ __launch_bounds__(256, 2) void flash_attn(
    const unsigned short* __restrict__ Qf,
    const unsigned short* __restrict__ Kf,
    const unsigned short* __restrict__ Vf,
    unsigned short* __restrict__ Y)
{
    const int tid  = threadIdx.x;
    const int wave = tid >> 6;
    const int lane = tid & 63;
    const int L  = blockIdx.x;
    const int bh = (L & 7) * 8 + ((L >> 3) & 7);
    const int x  = L >> 6;
    const int w  = x * 4 + wave;   // 0..31
    attn_pair(Qf, Kf, Vf, Y, bh, w, 63 - w, lane);
}

// ---------------- launch ----------------
extern "C" void kernel_launch(void* const* d_in, const int* in_sizes, int n_in,
                              void* d_out, int out_size, void* d_ws, size_t ws_size,
                              hipStream_t stream) {
    const float* x  = (const float*)d_in[0];
    const float* Wq = (const float*)d_in[1];
    const float* bq = (const float*)d_in[2];
    const float* Wk = (const float*)d_in[3];
    const float* bk = (const float*)d_in[4];
    const float* Wv = (const float*)d_in[5];
    const float* bv = (const float*)d_in[6];
    const float* Wo = (const float*)d_in[7];
    const float* bo = (const float*)d_in[8];

    char* ws = (char*)d_ws;
    size_t off = 0;
    auto alloc = [&](size_t bytes) -> void* {
        void* p = ws + off;
        off += (bytes + 255) & ~(size_t)255;
        return p;
    };
    unsigned short* xb  = (unsigned short*)alloc((size_t)NM * NC * 2);
    unsigned short* Wqb = (unsigned short*)alloc((size_t)NC * NC * 2);
    unsigned short* Wkb = (unsigned short*)alloc((size_t)NC * NC * 2);
    unsigned short* Wvb = (unsigned short*)alloc((size_t)NC * NC * 2);
    unsigned short* Wob = (unsigned short*)alloc((size_t)NC * NC * 2);
    unsigned short* Qb  = (unsigned short*)alloc((size_t)NM * NC * 2);
    unsigned short* Kb  = (unsigned short*)alloc((size_t)NM * NC * 2);
    unsigned short* Vtb = (unsigned short*)alloc((size_t)NM * NC * 2);
    unsigned short* Yb  = (unsigned short*)alloc((size_t)NM * NC * 2);

    // 16384 x-tiles + 4*2048 weight tiles = 24576 wave-tiles
    cast_all<<<(24576*64)/256, 256, 0, stream>>>(
        x, Wq, Wk, Wv, Wo, xb, Wqb, Wkb, Wvb, Wob);

    gemm_qkv<<<dim3(NM / TM, NC / TN), 256, 0, stream>>>(
        xb, Wqb, Wkb, Wvb, bq, bk, bv, Qb, Kb, Vtb);

    flash_attn<<<dim3(512), 256, 0, stream>>>(Qb, Kb, Vtb, Yb);

    gemm_out<<<dim3(NM / TM, NC / TN), 256, 0, stream>>>(Yb, Wob, bo, (float*)d_out);
}